// Round 16
// baseline (1485.384 us; speedup 1.0000x reference)
//
#include <hip/hip_runtime.h>
#include <cmath>

#define B_   128
#define C_   9
#define N_   2048
#define D_   192
#define H_   384
#define NC_  18

typedef unsigned short ushort_t;
typedef __attribute__((ext_vector_type(8))) __bf16 bf16x8;
typedef __attribute__((ext_vector_type(8))) short short8;
typedef __attribute__((ext_vector_type(16))) float f32x16;

__device__ __forceinline__ ushort_t f2bf(float x) {
    unsigned u = __float_as_uint(x);
    return (ushort_t)((u + 0x7fffu + ((u >> 16) & 1u)) >> 16);
}
__device__ __forceinline__ float bf2f(ushort_t h) {
    return __uint_as_float(((unsigned)h) << 16);
}
__device__ __forceinline__ bf16x8 ldfrag(const ushort_t* p) {
    short8 s = *(const short8*)p;
    return __builtin_bit_cast(bf16x8, s);
}

#define APL12 12288   // mgemm linear plane stride (24 k8 * 64 * 8)
#define APAD  12480   // fused_mlp padded plane stride (24 units * 520)

// ---------------------------------------------------------------------------
// conv1d(C->D,k=3,pad=1) + pos_embed + LayerNorm1 + hi/lo split, fully fused.
// ---------------------------------------------------------------------------
__global__ __launch_bounds__(192) void conv_ln_k(
    const float* __restrict__ x, const float* __restrict__ w,
    const float* __restrict__ cb, const float* __restrict__ pos,
    const float* __restrict__ lng, const float* __restrict__ lnb,
    float* __restrict__ h, ushort_t* __restrict__ oh, ushort_t* __restrict__ ol)
{
    const int n0 = blockIdx.x * 64;
    const int b  = blockIdx.y;
    const int d  = threadIdx.x;

    __shared__ float xs[C_][66];
    __shared__ float tile[64][193];
    __shared__ float ps[64][3], pq[64][3];
    __shared__ float mm[64], rr[64];

    for (int e = threadIdx.x; e < C_ * 66; e += 192) {
        int c = e / 66, i = e % 66;
        int n = n0 - 1 + i;
        xs[c][i] = (n >= 0 && n < N_) ? x[((size_t)b * C_ + c) * N_ + n] : 0.f;
    }
    float wr[C_][3];
#pragma unroll
    for (int c = 0; c < C_; ++c)
#pragma unroll
        for (int t = 0; t < 3; ++t) wr[c][t] = w[(d * C_ + c) * 3 + t];
    const float bias = cb[d];
    __syncthreads();

    for (int i = 0; i < 64; ++i) {
        float acc = bias + pos[(size_t)(n0 + i) * D_ + d];
#pragma unroll
        for (int c = 0; c < C_; ++c)
#pragma unroll
            for (int t = 0; t < 3; ++t) acc += xs[c][i + t] * wr[c][t];
        tile[i][d] = acc;
    }
    __syncthreads();

    {
        int row = threadIdx.x & 63, part = threadIdx.x >> 6;
        float s = 0.f, q = 0.f;
        const float* tr = &tile[row][part * 64];
#pragma unroll 8
        for (int j = 0; j < 64; ++j) { float v = tr[j]; s += v; q += v * v; }
        ps[row][part] = s; pq[row][part] = q;
    }
    __syncthreads();
    if (threadIdx.x < 64) {
        int r = threadIdx.x;
        float s = ps[r][0] + ps[r][1] + ps[r][2];
        float q = pq[r][0] + pq[r][1] + pq[r][2];
        float m = s * (1.f / D_);
        mm[r] = m;
        rr[r] = rsqrtf(q * (1.f / D_) - m * m + 1e-5f);
    }
    __syncthreads();
    {
        const float gd = lng[d], bd = lnb[d];
        for (int i = 0; i < 64; ++i) {
            float v = tile[i][d];
            size_t idx = ((size_t)b * N_ + n0 + i) * D_ + d;
            h[idx] = v;
            float nv = (v - mm[i]) * rr[i] * gd + bd;
            ushort_t hb = f2bf(nv);
            oh[idx] = hb;
            ol[idx] = f2bf(nv - bf2f(hb));
        }
    }
}

// ---------------------------------------------------------------------------
// split f32 weights -> hi/lo bf16 planes in MFMA fragment-packed layout
// ---------------------------------------------------------------------------
__global__ __launch_bounds__(256) void splitw_pack_k(
    const float* __restrict__ w, ushort_t* __restrict__ hi, ushort_t* __restrict__ lo,
    int NW, int K)
{
    int i = blockIdx.x * 256 + threadIdx.x;
    if (i >= NW * K) return;
    int row = i / K, k = i % K;
    int g = row / 192, c = row % 192;
    float v = w[i];
    ushort_t hb = f2bf(v);
    size_t o = (size_t)g * K * 192 + (size_t)(k >> 4) * 3072 + (size_t)c * 16 + (k & 15);
    hi[o] = hb;
    lo[o] = f2bf(v - bf2f(hb));
}

// ---------------------------------------------------------------------------
// Split-bf16 MFMA GEMM, A-resident LDS, W packed-global DEPTH-6 prefetch.
// EPI 0: qkv (by0 q bounce-store + qsum; by1/2 k/v transposed split).
// EPI 3: v = h + acc/(sum dsum)+bias (no h write-back: final h is dead);
//        pool partial of v; fused LN2 + split -> bounce-store hn.
// ---------------------------------------------------------------------------
template <int EPI, int KT, int NBY>
__global__ __launch_bounds__(256) void mgemm(
    const ushort_t* __restrict__ Ah, const ushort_t* __restrict__ Al,
    const ushort_t* __restrict__ Wh, const ushort_t* __restrict__ Wl,
    const float* __restrict__ bias, float* __restrict__ dsum,
    const float* __restrict__ lng, const float* __restrict__ lnb,
    ushort_t* __restrict__ oh, ushort_t* __restrict__ ol,
    ushort_t* __restrict__ kTh, ushort_t* __restrict__ kTl,
    ushort_t* __restrict__ vTh, ushort_t* __restrict__ vTl,
    const float* __restrict__ facc, float* __restrict__ pooledp)
{
    extern __shared__ ushort_t smem[];
    constexpr int NS  = KT / 16;
    constexpr int APL = APL12;
    constexpr int PD  = (NS < 6) ? NS : 6;     // W prefetch depth

    const int tid  = threadIdx.x;
    const int lane = tid & 63;
    const int l5   = lane >> 5;
    const int wid  = tid >> 6;
    const int wr = wid >> 1, wc = wid & 1;

    int bx, by;
    {
        int gmx = gridDim.x / NBY;
        int xx = blockIdx.x & 7, ii = blockIdx.x >> 3;
        by = ii % NBY;
        bx = xx * (gmx >> 3) + ii / NBY;
    }
    const int m0 = bx * 64;
    const int batch = m0 >> 11;

    size_t wbase = 0;
    if (EPI == 0) wbase = (size_t)by * 192 * KT;
    else if (EPI == 3) wbase = (size_t)batch * D_ * D_;
    const ushort_t* Whp = Wh + wbase;
    const ushort_t* Wlp = Wl + wbase;

    auto stageChunk = [&](int kr) {
#pragma unroll
        for (int i = 0; i < 12; ++i) {
            int c = wid + i * 4;
            int plane = c & 1, k8 = c >> 1;
            const ushort_t* ap = plane ? Al : Ah;
            const ushort_t* src = ap + (size_t)(m0 + lane) * KT + kr * 192 + k8 * 8;
            __builtin_amdgcn_global_load_lds(
                (const __attribute__((address_space(1))) void*)src,
                (__attribute__((address_space(3))) void*)(smem + plane * APL + k8 * 512),
                16, 0, 0);
        }
    };

    const int wcol = (wc * 96 + (lane & 31)) * 16 + l5 * 8;
    auto loadW = [&](int sg, bf16x8* w) {
#pragma unroll
        for (int tn = 0; tn < 3; ++tn) {
            size_t off = (size_t)sg * 3072 + wcol + tn * 512;
            w[tn * 2 + 0] = ldfrag(Whp + off);
            w[tn * 2 + 1] = ldfrag(Wlp + off);
        }
    };

    f32x16 acc[3] = {};
    const int arow = (wr * 32 + (lane & 31)) * 8;

    bf16x8 wb[PD][6];
#pragma unroll
    for (int k = 0; k < PD; ++k) loadW(k, wb[k]);

#pragma unroll
    for (int s = 0; s < NS; ++s) {
        if ((s % 12) == 0) {
            if (s) __syncthreads();
            stageChunk(s / 12);
            __syncthreads();
        }
        bf16x8* wcur = wb[s % PD];
        int ao = ((s % 12) * 2 + l5) * 512 + arow;
        bf16x8 ah = ldfrag(smem + ao);
        bf16x8 al = ldfrag(smem + APL + ao);
#pragma unroll
        for (int tn = 0; tn < 3; ++tn) {
            acc[tn] = __builtin_amdgcn_mfma_f32_32x32x16_bf16(ah, wcur[tn * 2 + 0], acc[tn], 0, 0, 0);
            acc[tn] = __builtin_amdgcn_mfma_f32_32x32x16_bf16(ah, wcur[tn * 2 + 1], acc[tn], 0, 0, 0);
            acc[tn] = __builtin_amdgcn_mfma_f32_32x32x16_bf16(al, wcur[tn * 2 + 0], acc[tn], 0, 0, 0);
        }
        if (s + PD < NS) loadW(s + PD, wcur);
    }

    const int cb = wc * 96 + (lane & 31);
    const int rb0 = m0 + wr * 32 + 4 * l5;
    const int rl0 = wr * 32 + 4 * l5;

    if (EPI == 0) {
        if (by == 0) {
            float qsum = 0.f;
            __syncthreads();
#pragma unroll
            for (int tn = 0; tn < 3; ++tn) {
                const int col = cb + tn * 32;
                const float bv = bias[col];
#pragma unroll
                for (int r = 0; r < 16; ++r) {
                    int rowl = rl0 + (r & 3) + 8 * (r >> 2);
                    float v = fmaxf(acc[tn][r] + bv, 0.f);
                    qsum += v;
                    ushort_t hb = f2bf(v);
                    smem[rowl * 192 + col] = hb;
                    smem[APL + rowl * 192 + col] = f2bf(v - bf2f(hb));
                }
            }
            __syncthreads();
            {
                size_t gb = (size_t)m0 * 192;
#pragma unroll
                for (int j = 0; j < 6; ++j) {
                    int idx = (tid * 6 + j) * 8;
                    *(uint4*)(oh + gb + idx) = *(const uint4*)&smem[idx];
                    *(uint4*)(ol + gb + idx) = *(const uint4*)&smem[APL + idx];
                }
            }
            float* red = (float*)(smem + 2 * APL);
            red[tid] = qsum;
            __syncthreads();
            for (int o = 128; o > 0; o >>= 1) {
                if (tid < o) red[tid] += red[tid + o];
                __syncthreads();
            }
            if (tid == 0) dsum[batch * 32 + ((m0 >> 6) & 31)] = red[0];
        } else {
            ushort_t* dsth = (by == 1) ? kTh : vTh;
            ushort_t* dstl = (by == 1) ? kTl : vTl;
            constexpr int STR = 72;
#pragma unroll
            for (int plane = 0; plane < 2; ++plane) {
                __syncthreads();
#pragma unroll
                for (int tn = 0; tn < 3; ++tn) {
                    const int col = cb + tn * 32;
                    const float bv = bias[by * 192 + col];
#pragma unroll
                    for (int r = 0; r < 16; ++r) {
                        int rowl = rl0 + (r & 3) + 8 * (r >> 2);
                        float v = acc[tn][r] + bv;
                        if (by == 1) v = fmaxf(v, 0.f);
                        ushort_t hb = f2bf(v);
                        smem[col * STR + rowl] = plane ? f2bf(v - bf2f(hb)) : hb;
                    }
                }
                __syncthreads();
                if (tid < 192) {
                    ushort_t* dst = plane ? dstl : dsth;
                    size_t gbase = ((size_t)batch * 192 + tid) * (size_t)N_ + (m0 & 2047);
#pragma unroll
                    for (int i2 = 0; i2 < 8; ++i2)
                        *(uint4*)(dst + gbase + i2 * 8) = *(const uint4*)&smem[tid * STR + i2 * 8];
                }
            }
        }
    } else if (EPI == 3) {
        float ds = 0.f;
        const float* dp = dsum + batch * 32;
#pragma unroll
        for (int j = 0; j < 32; ++j) ds += dp[j];
        const float s = 1.f / (ds + 1e-6f);
        float tsum[3] = {0.f, 0.f, 0.f};
#pragma unroll
        for (int tn = 0; tn < 3; ++tn) {
            const int col = cb + tn * 32;
            const float bv = bias[col];
#pragma unroll
            for (int r = 0; r < 16; ++r) {
                int row = rb0 + (r & 3) + 8 * (r >> 2);
                float v = facc[(size_t)row * D_ + col] + acc[tn][r] * s + bv;
                acc[tn][r] = v;
                tsum[tn] += v;
            }
        }
#pragma unroll
        for (int tn = 0; tn < 3; ++tn) {
            float t = tsum[tn];
            t += __shfl_xor(t, 32);
            if (l5 == 0) atomicAdd(&pooledp[(size_t)batch * D_ + cb + tn * 32], t);
        }
        __syncthreads();
        float* ls = (float*)(smem + 2 * APL);
        float* lq = ls + 128;
        float* lm = lq + 128;
        float* lr = lm + 64;
#pragma unroll
        for (int r = 0; r < 16; ++r) {
            float pv = acc[0][r] + acc[1][r] + acc[2][r];
            float qv = acc[0][r] * acc[0][r] + acc[1][r] * acc[1][r] + acc[2][r] * acc[2][r];
#pragma unroll
            for (int off = 1; off <= 16; off <<= 1) {
                pv += __shfl_xor(pv, off);
                qv += __shfl_xor(qv, off);
            }
            if ((lane & 31) == 0) {
                int rl = rl0 + (r & 3) + 8 * (r >> 2);
                ls[rl * 2 + wc] = pv;
                lq[rl * 2 + wc] = qv;
            }
        }
        __syncthreads();
        if (tid < 64) {
            float sv = ls[tid * 2] + ls[tid * 2 + 1];
            float qv = lq[tid * 2] + lq[tid * 2 + 1];
            float mv = sv * (1.f / D_);
            lm[tid] = mv;
            lr[tid] = rsqrtf(qv * (1.f / D_) - mv * mv + 1e-5f);
        }
        __syncthreads();
#pragma unroll
        for (int tn = 0; tn < 3; ++tn) {
            const int col = cb + tn * 32;
            const float gv = lng[col], bv2 = lnb[col];
#pragma unroll
            for (int r = 0; r < 16; ++r) {
                int rl = rl0 + (r & 3) + 8 * (r >> 2);
                float nv = (acc[tn][r] - lm[rl]) * lr[rl] * gv + bv2;
                ushort_t hb = f2bf(nv);
                smem[rl * 192 + col] = hb;
                smem[APL + rl * 192 + col] = f2bf(nv - bf2f(hb));
            }
        }
        __syncthreads();
        {
            size_t gb = (size_t)m0 * 192;
#pragma unroll
            for (int j = 0; j < 6; ++j) {
                int idx = (tid * 6 + j) * 8;
                *(uint4*)(oh + gb + idx) = *(const uint4*)&smem[idx];
                *(uint4*)(ol + gb + idx) = *(const uint4*)&smem[APL + idx];
            }
        }
    }
}

// ---------------------------------------------------------------------------
// Fused MLP, group-split, no h materialization. Block (bx,g):
// m_g = gelu(hn@W1_g^T+b1_g); partial mlp2 over K-half g; pool atomics.
// W2 preloads issued BEFORE the gelu bounce (latency hidden under bounce).
// ---------------------------------------------------------------------------
__global__ __launch_bounds__(256) void fused_mlp_g(
    const ushort_t* __restrict__ Ah, const ushort_t* __restrict__ Al,
    const ushort_t* __restrict__ W1h, const ushort_t* __restrict__ W1l,
    const ushort_t* __restrict__ W2h, const ushort_t* __restrict__ W2l,
    const float* __restrict__ b1, const float* __restrict__ b2,
    float* __restrict__ pooled)
{
    extern __shared__ ushort_t smem[];

    const int tid  = threadIdx.x;
    const int lane = tid & 63;
    const int l5   = lane >> 5;
    const int wid  = tid >> 6;
    const int wr = wid >> 1, wc = wid & 1;

    int bx, g;
    {
        int gmx = gridDim.x / 2;
        int xx = blockIdx.x & 7, ii = blockIdx.x >> 3;
        g = ii & 1;
        bx = xx * (gmx >> 3) + (ii >> 1);
    }
    const int m0 = bx * 64;
    const int batch = m0 >> 11;

    // stage hn panel (K=192, both planes), padded units
#pragma unroll
    for (int i = 0; i < 12; ++i) {
        int c = wid + i * 4;
        int plane = c & 1, k8 = c >> 1;
        const ushort_t* ap = plane ? Al : Ah;
        const ushort_t* src = ap + (size_t)(m0 + lane) * 192 + k8 * 8;
        __builtin_amdgcn_global_load_lds(
            (const __attribute__((address_space(1))) void*)src,
            (__attribute__((address_space(3))) void*)(smem + plane * APAD + k8 * 520),
            16, 0, 0);
    }

    const int wcol = (wc * 96 + (lane & 31)) * 16 + l5 * 8;
    const int arow = (wr * 32 + (lane & 31)) * 8;

    auto loadWf = [&](const ushort_t* Wh, const ushort_t* Wl, int sg, bf16x8* w) {
#pragma unroll
        for (int tn = 0; tn < 3; ++tn) {
            size_t off = (size_t)sg * 3072 + wcol + tn * 512;
            w[tn * 2 + 0] = ldfrag(Wh + off);
            w[tn * 2 + 1] = ldfrag(Wl + off);
        }
    };

    const ushort_t* Wg1h = W1h + g * 36864;
    const ushort_t* Wg1l = W1l + g * 36864;

    bf16x8 w0[6], w1[6], w2[6];
    loadWf(Wg1h, Wg1l, 0, w0);
    loadWf(Wg1h, Wg1l, 1, w1);
    loadWf(Wg1h, Wg1l, 2, w2);
    __syncthreads();

    // ---- mlp1 (group g) ----
    f32x16 accm[3] = {};
#pragma unroll
    for (int s = 0; s < 12; ++s) {
        bf16x8* wcur = (s % 3 == 0) ? w0 : ((s % 3 == 1) ? w1 : w2);
        int ao = (s * 2 + l5) * 520 + arow;
        bf16x8 ah = ldfrag(smem + ao);
        bf16x8 al = ldfrag(smem + APAD + ao);
#pragma unroll
        for (int tn = 0; tn < 3; ++tn) {
            accm[tn] = __builtin_amdgcn_mfma_f32_32x32x16_bf16(ah, wcur[tn * 2 + 0], accm[tn], 0, 0, 0);
            accm[tn] = __builtin_amdgcn_mfma_f32_32x32x16_bf16(ah, wcur[tn * 2 + 1], accm[tn], 0, 0, 0);
            accm[tn] = __builtin_amdgcn_mfma_f32_32x32x16_bf16(al, wcur[tn * 2 + 0], accm[tn], 0, 0, 0);
        }
        if (s + 3 < 12) loadWf(Wg1h, Wg1l, s + 3, wcur);
    }

    // ---- W2 preloads issued before the bounce (latency hidden) ----
    loadWf(W2h, W2l, g * 12 + 0, w0);
    loadWf(W2h, W2l, g * 12 + 1, w1);
    loadWf(W2h, W2l, g * 12 + 2, w2);

    // ---- gelu bounce m_g through padded LDS ----
    __syncthreads();
#pragma unroll
    for (int tn = 0; tn < 3; ++tn) {
        const int cl = wc * 96 + tn * 32 + (lane & 31);
        const float bv = b1[g * 192 + cl];
#pragma unroll
        for (int r = 0; r < 16; ++r) {
            int rowl = wr * 32 + 4 * l5 + (r & 3) + 8 * (r >> 2);
            float v = accm[tn][r] + bv;
            float gv = 0.5f * v * (1.f + erff(v * 0.70710678118654752f));
            ushort_t hb = f2bf(gv);
            int ad = (cl >> 3) * 520 + rowl * 8 + (cl & 7);
            smem[ad] = hb;
            smem[APAD + ad] = f2bf(gv - bf2f(hb));
        }
    }
    __syncthreads();

    // ---- mlp2 partial over K-half g ----
    f32x16 acco[3] = {};
#pragma unroll
    for (int s = 0; s < 12; ++s) {
        bf16x8* wcur = (s % 3 == 0) ? w0 : ((s % 3 == 1) ? w1 : w2);
        int ao = (s * 2 + l5) * 520 + arow;
        bf16x8 ah = ldfrag(smem + ao);
        bf16x8 al = ldfrag(smem + APAD + ao);
#pragma unroll
        for (int tn = 0; tn < 3; ++tn) {
            acco[tn] = __builtin_amdgcn_mfma_f32_32x32x16_bf16(ah, wcur[tn * 2 + 0], acco[tn], 0, 0, 0);
            acco[tn] = __builtin_amdgcn_mfma_f32_32x32x16_bf16(ah, wcur[tn * 2 + 1], acco[tn], 0, 0, 0);
            acco[tn] = __builtin_amdgcn_mfma_f32_32x32x16_bf16(al, wcur[tn * 2 + 0], acco[tn], 0, 0, 0);
        }
        if (s + 3 < 12) loadWf(W2h, W2l, g * 12 + s + 3, wcur);
    }

    // ---- epilogue: pool partials only ----
    const int cb = wc * 96 + (lane & 31);
#pragma unroll
    for (int tn = 0; tn < 3; ++tn) {
        const int col = cb + tn * 32;
        float t = (g == 0) ? 16.f * b2[col] : 0.f;
#pragma unroll
        for (int r = 0; r < 16; ++r) t += acco[tn][r];
        t += __shfl_xor(t, 32);
        if (l5 == 0) atomicAdd(&pooled[(size_t)batch * D_ + col], t);
    }
}

// ---------------------------------------------------------------------------
// kv slab GEMM: kvslab[z][b,d,e], both operands LDS-staged, BK=32 dbuf.
// ---------------------------------------------------------------------------
__global__ __launch_bounds__(256) void mgemm_kv(
    const ushort_t* __restrict__ Ah, const ushort_t* __restrict__ Al,
    const ushort_t* __restrict__ Wh, const ushort_t* __restrict__ Wl,
    float* __restrict__ facc, size_t span)
{
    extern __shared__ ushort_t smem[];
    constexpr int BM = 64;
    constexpr int APL = BM * 32, AK = BM * 8, AELEMS = BM * 64;
    constexpr int BUFE = AELEMS + 12288;
    constexpr int ACH = 8, NCH = ACH + 24;

    const int tid  = threadIdx.x;
    const int lane = tid & 63;
    const int l5   = lane >> 5;
    const int wid  = tid >> 6;
    const int wr = wid >> 1, wc = wid & 1;
    const int bx = blockIdx.x;
    const int m0 = bx * BM;

    const size_t wbase = (size_t)(bx / 3) * 192 * (size_t)N_;
    const ushort_t* Whp = Wh + wbase;
    const ushort_t* Wlp = Wl + wbase;

    const int seg = N_ / gridDim.z;
    const int kbeg = blockIdx.z * seg, kend = kbeg + seg;

    auto stage = [&](int buf, int k0) {
        const int base = buf * BUFE;
#pragma unroll
        for (int i = 0; i < NCH / 4; ++i) {
            int c = wid + i * 4;
            const ushort_t* src;
            int dst;
            if (c < ACH) {
                int koct = c & 3, tt = c >> 2;
                int plane = tt & 1;
                const ushort_t* ap = plane ? Al : Ah;
                src = ap + (size_t)(m0 + lane) * N_ + k0 + koct * 8;
                dst = plane * APL + koct * AK;
            } else {
                int c2 = c - ACH;
                int koct = c2 & 3, tt = c2 >> 2;
                int plane = tt & 1, rb = tt >> 1;
                const ushort_t* wp = plane ? Wlp : Whp;
                src = wp + (size_t)(rb * 64 + lane) * N_ + k0 + koct * 8;
                dst = AELEMS + plane * 6144 + koct * 1536 + rb * 512;
            }
            __builtin_amdgcn_global_load_lds(
                (const __attribute__((address_space(1))) void*)src,
                (__attribute__((address_space(3))) void*)(smem + base + dst),
                16, 0, 0);
        }
    };

    f32x16 acc[3] = {};

    const int nt = (kend - kbeg) / 32;
    stage(0, kbeg);
    __syncthreads();
    int cur = 0;
    for (int t = 0; t < nt; ++t) {
        if (t + 1 < nt) stage(cur ^ 1, kbeg + (t + 1) * 32);
        const ushort_t* bb = smem + cur * BUFE;
#pragma unroll
        for (int kh = 0; kh < 2; ++kh) {
            int ao = (kh * 2 + l5) * AK + (wr * 32 + (lane & 31)) * 8;
            bf16x8 ah = ldfrag(bb + ao);
            bf16x8 al = ldfrag(bb + APL + ao);
#pragma unroll
            for (int tn = 0; tn < 3; ++tn) {
                int wo = AELEMS + (kh * 2 + l5) * 1536 + (wc * 96 + tn * 32 + (lane & 31)) * 8;
                bf16x8 wh = ldfrag(bb + wo);
                bf16x8 wl = ldfrag(bb + wo + 6144);
                acc[tn] = __builtin_amdgcn_mfma_f32_32x32x16_bf16(ah, wh, acc[tn], 0, 0, 0);
                acc[tn] = __builtin_amdgcn_mfma_f32_32x32x16_bf16(ah, wl, acc[tn], 0, 0, 0);
                acc[tn] = __builtin_amdgcn_mfma_f32_32x32x16_bf16(al, wh, acc[tn], 0, 0, 0);
            }
        }
        __syncthreads();
        cur ^= 1;
    }

    float* fz = facc + (size_t)blockIdx.z * span;
    const int cb = wc * 96 + (lane & 31);
    const int rb0 = m0 + wr * 32 + 4 * l5;
#pragma unroll
    for (int tn = 0; tn < 3; ++tn) {
        const int col = cb + tn * 32;
#pragma unroll
        for (int r = 0; r < 16; ++r) {
            int row = rb0 + (r & 3) + 8 * (r >> 2);
            fz[(size_t)row * D_ + col] = acc[tn][r];
        }
    }
}

// ---------------------------------------------------------------------------
// kv2T[b,e,d] = sum_f proj_w[e,f] * (sum_z kvslab[z][b,d,f]) -> packed split
// ---------------------------------------------------------------------------
__global__ __launch_bounds__(256) void kv2_k(
    const float* __restrict__ pw, const float* __restrict__ kvs, size_t span,
    ushort_t* __restrict__ oh, ushort_t* __restrict__ ol)
{
    __shared__ float As[16][68];
    __shared__ float Ws[16][68];
    const int tid = threadIdx.x;
    const int tx = tid & 15, ty = tid >> 4;
    const int m0 = blockIdx.x * 64;   // e
    const int n0 = blockIdx.y * 64;   // d
    const int b = blockIdx.z;
    const int lm = tid >> 2;
    const int lk = (tid & 3) * 4;

    float acc[4][4] = {};
    for (int k0 = 0; k0 < D_; k0 += 16) {
        float4 av = *(const float4*)(pw + (size_t)(m0 + lm) * D_ + k0 + lk);
        As[lk + 0][lm] = av.x; As[lk + 1][lm] = av.y;
        As[lk + 2][lm] = av.z; As[lk + 3][lm] = av.w;
        const float* base = kvs + (size_t)b * D_ * D_ + (size_t)(n0 + lm) * D_ + k0 + lk;
        float4 wv = {0.f, 0.f, 0.f, 0.f};
#pragma unroll
        for (int z = 0; z < 8; ++z) {
            float4 t = *(const float4*)(base + z * span);
            wv.x += t.x; wv.y += t.y; wv.z += t.z; wv.w += t.w;
        }
        Ws[lk + 0][lm] = wv.x; Ws[lk + 1][lm] = wv.y;
        Ws[lk + 2][lm] = wv.z; Ws[lk + 3][lm] = wv.w;
        __syncthreads();
#pragma unroll
        for (int kk = 0; kk < 16; ++kk) {
            float4 a4 = *(const float4*)&As[kk][ty * 4];
            float4 w4 = *(const float4*)&Ws[kk][tx * 4];
            float a[4] = {a4.x, a4.y, a4.z, a4.w};
            float w[4] = {w4.x, w4.y, w4.z, w4.w};
#pragma unroll
            for (int i = 0; i < 4; ++i)
#pragma unroll
                for (int j = 0; j < 4; ++j) acc[i][j] += a[i] * w[j];
        }
        __syncthreads();
    }
    const int d0 = n0 + tx * 4;
#pragma unroll
    for (int i = 0; i < 4; ++i) {
        ushort_t hb[4], lb[4];
#pragma unroll
        for (int j = 0; j < 4; ++j) {
            float v = acc[i][j];
            hb[j] = f2bf(v);
            lb[j] = f2bf(v - bf2f(hb[j]));
        }
        const int e = m0 + ty * 4 + i;
        size_t off = (size_t)b * D_ * D_ + ((size_t)(d0 >> 4) * 192 + e) * 16 + (d0 & 15);
        *(uint2*)&oh[off] = make_uint2((unsigned)hb[0] | ((unsigned)hb[1] << 16),
                                       (unsigned)hb[2] | ((unsigned)hb[3] << 16));
        *(uint2*)&ol[off] = make_uint2((unsigned)lb[0] | ((unsigned)lb[1] << 16),
                                       (unsigned)lb[2] | ((unsigned)lb[3] << 16));
    }
}

// ---------------------------------------------------------------------------
__global__ __launch_bounds__(192) void head_k(
    const float* __restrict__ pooled, const float* __restrict__ hw,
    const float* __restrict__ hb, float* __restrict__ out)
{
    const int b = blockIdx.x, d = threadIdx.x;
    __shared__ float p[D_];
    p[d] = pooled[(size_t)b * D_ + d] * (1.f / N_);
    __syncthreads();
    if (d < NC_) {
        float acc = hb[d];
        for (int e = 0; e < D_; ++e) acc += p[e] * hw[d * D_ + e];
        out[b * NC_ + d] = acc;
    }
}

// ---------------------------------------------------------------------------
extern "C" void kernel_launch(void* const* d_in, const int* in_sizes, int n_in,
                              void* d_out, int out_size, void* d_ws, size_t ws_size,
                              hipStream_t stream) {
    (void)in_sizes; (void)n_in; (void)out_size;

    const float* x      = (const float*)d_in[0];
    const float* conv_w = (const float*)d_in[1];
    const float* conv_b = (const float*)d_in[2];
    const float* pos    = (const float*)d_in[3];
    const float* qkv_w  = (const float*)d_in[4];
    const float* qkv_b  = (const float*)d_in[5];
    const float* proj_w = (const float*)d_in[6];
    const float* proj_b = (const float*)d_in[7];
    const float* ln1_g  = (const float*)d_in[8];
    const float* ln1_b  = (const float*)d_in[9];
    const float* mlp_w1 = (const float*)d_in[10];
    const float* mlp_b1 = (const float*)d_in[11];
    const float* mlp_w2 = (const float*)d_in[12];
    const float* mlp_b2 = (const float*)d_in[13];
    const float* ln2_g  = (const float*)d_in[14];
    const float* ln2_b  = (const float*)d_in[15];
    const float* head_w = (const float*)d_in[16];
    const float* head_b = (const float*)d_in[17];
    float* out = (float*)d_out;

    const size_t perB =
        (size_t)N_ * D_ * 4 +            // h
        (size_t)N_ * D_ * 2 * 2 +        // hn hi+lo (aliased by kv slabs)
        (size_t)N_ * D_ * 2 * 2 +        // q hi+lo
        (size_t)N_ * D_ * 2 * 4 +        // kT,vT hi+lo
        (size_t)D_ * D_ * 2 * 2 +        // kv2t hi+lo (packed)
        16384;
    const size_t fixedW = 2ull * (576 * 192 + 384 * 192 + 192 * 384) * 2 + 65536;
    int BC = B_;
    while (BC > 1 && fixedW + (size_t)BC * perB > ws_size) BC >>= 1;
    const int nchunks = B_ / BC;
    const size_t rows = (size_t)BC * N_;

    char* p = (char*)d_ws;
    auto alloc = [&](size_t bytes) -> char* {
        char* r = p;
        p += (bytes + 255) & ~(size_t)255;
        return r;
    };
    ushort_t* qw_hi = (ushort_t*)alloc(576 * 192 * 2);
    ushort_t* qw_lo = (ushort_t*)alloc(576 * 192 * 2);
    ushort_t* w1_hi = (ushort_t*)alloc(384 * 192 * 2);
    ushort_t* w1_lo = (ushort_t*)alloc(384 * 192 * 2);
    ushort_t* w2_hi = (ushort_t*)alloc(192 * 384 * 2);
    ushort_t* w2_lo = (ushort_t*)alloc(192 * 384 * 2);

    const size_t szPl = rows * D_ * 2;
    float*    h      = (float*)alloc(rows * D_ * 4);
    ushort_t* hn_hi  = (ushort_t*)alloc(szPl);
    ushort_t* hn_lo  = (ushort_t*)alloc(szPl);
    ushort_t* q_hi   = (ushort_t*)alloc(szPl);
    ushort_t* q_lo   = (ushort_t*)alloc(szPl);
    ushort_t* kT_hi  = (ushort_t*)alloc(szPl);
    ushort_t* kT_lo  = (ushort_t*)alloc(szPl);
    ushort_t* vT_hi  = (ushort_t*)alloc(szPl);
    ushort_t* vT_lo  = (ushort_t*)alloc(szPl);
    ushort_t* kv2t_h = (ushort_t*)alloc((size_t)BC * D_ * D_ * 2);
    ushort_t* kv2t_l = (ushort_t*)alloc((size_t)BC * D_ * D_ * 2);
    float*    dsum   = (float*)alloc((size_t)BC * 32 * 4);
    float*    pooled = (float*)alloc((size_t)BC * D_ * 4);
    float*    kvs    = (float*)hn_hi;       // 8 kv slabs alias hn (dead there)
    const size_t kvspan = (size_t)BC * D_ * D_;

    splitw_pack_k<<<(576 * 192 + 255) / 256, 256, 0, stream>>>(qkv_w, qw_hi, qw_lo, 576, 192);
    splitw_pack_k<<<(384 * 192 + 255) / 256, 256, 0, stream>>>(mlp_w1, w1_hi, w1_lo, 384, 192);
    splitw_pack_k<<<(192 * 384 + 255) / 256, 256, 0, stream>>>(mlp_w2, w2_hi, w2_lo, 192, 384);

    const int gm = (int)(rows / 64);
    const size_t SHQ = 50688;                              // mgemm planes + scratch
    const size_t SHG = (size_t)APAD * 2 * 2;               // fused_mlp_g padded planes
    const size_t SH4 = (size_t)(64 * 64 + 12288) * 2 * 2;  // kv dbuf

    for (int ch = 0; ch < nchunks; ++ch) {
        const int b0 = ch * BC;
        const float* xc = x + (size_t)b0 * C_ * N_;

        hipMemsetAsync(pooled, 0, (size_t)BC * D_ * 4, stream);

        // 1. conv + pos + LN1 + split
        conv_ln_k<<<dim3(N_ / 64, BC), 192, 0, stream>>>(
            xc, conv_w, conv_b, pos, ln1_g, ln1_b, h, hn_hi, hn_lo);
        // 2. qkv: q split + qsum slots; k,v transposed split
        mgemm<0, 192, 3><<<gm * 3, 256, SHQ, stream>>>(
            hn_hi, hn_lo, qw_hi, qw_lo, qkv_b, dsum, nullptr, nullptr,
            q_hi, q_lo, kT_hi, kT_lo, vT_hi, vT_lo, nullptr, nullptr);
        // 3. kv z-slabs = k^T v (K-split 8, plain stores into hn-aliased slabs)
        mgemm_kv<<<dim3(BC * 3, 1, 8), 256, SH4, stream>>>(
            kT_hi, kT_lo, vT_hi, vT_lo, kvs, kvspan);
        // 4. kv2T = proj_w @ (sum slabs)^T -> packed split
        kv2_k<<<dim3(3, 3, BC), 256, 0, stream>>>(proj_w, kvs, kvspan, kv2t_h, kv2t_l);
        // 5. v = h + (q@kv2)/denom + proj_b; pool partial of v; LN2+split -> hn
        mgemm<3, 192, 1><<<gm, 256, SHQ, stream>>>(
            q_hi, q_lo, kv2t_h, kv2t_l, proj_b, dsum, ln2_g, ln2_b,
            hn_hi, hn_lo, nullptr, nullptr, nullptr, nullptr, h, pooled);
        // 6. fused MLP group-split: pool += mlp partial sums (no h writes)
        fused_mlp_g<<<gm * 2, 256, SHG, stream>>>(
            hn_hi, hn_lo, w1_hi, w1_lo, w2_hi, w2_lo, mlp_b1, mlp_b2, pooled);
        // 7. head
        head_k<<<BC, 192, 0, stream>>>(pooled, head_w, head_b, out + (size_t)b0 * NC_);
    }
}

// Round 17
// 1457.771 us; speedup vs baseline: 1.0189x; 1.0189x over previous
//
#include <hip/hip_runtime.h>
#include <cmath>

#define B_   128
#define C_   9
#define N_   2048
#define D_   192
#define H_   384
#define NC_  18

typedef unsigned short ushort_t;
typedef __attribute__((ext_vector_type(8))) __bf16 bf16x8;
typedef __attribute__((ext_vector_type(8))) short short8;
typedef __attribute__((ext_vector_type(16))) float f32x16;

__device__ __forceinline__ ushort_t f2bf(float x) {
    unsigned u = __float_as_uint(x);
    return (ushort_t)((u + 0x7fffu + ((u >> 16) & 1u)) >> 16);
}
__device__ __forceinline__ float bf2f(ushort_t h) {
    return __uint_as_float(((unsigned)h) << 16);
}
__device__ __forceinline__ bf16x8 ldfrag(const ushort_t* p) {
    short8 s = *(const short8*)p;
    return __builtin_bit_cast(bf16x8, s);
}

#define APL12 12288   // mgemm linear plane stride (24 k8 * 64 * 8)
#define APAD  12480   // fused_mlp padded plane stride (24 units * 520)

// ---------------------------------------------------------------------------
// conv1d(C->D,k=3,pad=1) + pos_embed + LayerNorm1 + hi/lo split, fully fused.
// ---------------------------------------------------------------------------
__global__ __launch_bounds__(192) void conv_ln_k(
    const float* __restrict__ x, const float* __restrict__ w,
    const float* __restrict__ cb, const float* __restrict__ pos,
    const float* __restrict__ lng, const float* __restrict__ lnb,
    float* __restrict__ h, ushort_t* __restrict__ oh, ushort_t* __restrict__ ol)
{
    const int n0 = blockIdx.x * 64;
    const int b  = blockIdx.y;
    const int d  = threadIdx.x;

    __shared__ float xs[C_][66];
    __shared__ float tile[64][193];
    __shared__ float ps[64][3], pq[64][3];
    __shared__ float mm[64], rr[64];

    for (int e = threadIdx.x; e < C_ * 66; e += 192) {
        int c = e / 66, i = e % 66;
        int n = n0 - 1 + i;
        xs[c][i] = (n >= 0 && n < N_) ? x[((size_t)b * C_ + c) * N_ + n] : 0.f;
    }
    float wr[C_][3];
#pragma unroll
    for (int c = 0; c < C_; ++c)
#pragma unroll
        for (int t = 0; t < 3; ++t) wr[c][t] = w[(d * C_ + c) * 3 + t];
    const float bias = cb[d];
    __syncthreads();

    for (int i = 0; i < 64; ++i) {
        float acc = bias + pos[(size_t)(n0 + i) * D_ + d];
#pragma unroll
        for (int c = 0; c < C_; ++c)
#pragma unroll
            for (int t = 0; t < 3; ++t) acc += xs[c][i + t] * wr[c][t];
        tile[i][d] = acc;
    }
    __syncthreads();

    {
        int row = threadIdx.x & 63, part = threadIdx.x >> 6;
        float s = 0.f, q = 0.f;
        const float* tr = &tile[row][part * 64];
#pragma unroll 8
        for (int j = 0; j < 64; ++j) { float v = tr[j]; s += v; q += v * v; }
        ps[row][part] = s; pq[row][part] = q;
    }
    __syncthreads();
    if (threadIdx.x < 64) {
        int r = threadIdx.x;
        float s = ps[r][0] + ps[r][1] + ps[r][2];
        float q = pq[r][0] + pq[r][1] + pq[r][2];
        float m = s * (1.f / D_);
        mm[r] = m;
        rr[r] = rsqrtf(q * (1.f / D_) - m * m + 1e-5f);
    }
    __syncthreads();
    {
        const float gd = lng[d], bd = lnb[d];
        for (int i = 0; i < 64; ++i) {
            float v = tile[i][d];
            size_t idx = ((size_t)b * N_ + n0 + i) * D_ + d;
            h[idx] = v;
            float nv = (v - mm[i]) * rr[i] * gd + bd;
            ushort_t hb = f2bf(nv);
            oh[idx] = hb;
            ol[idx] = f2bf(nv - bf2f(hb));
        }
    }
}

// ---------------------------------------------------------------------------
// split f32 weights -> hi/lo bf16 planes in MFMA fragment-packed layout
// ---------------------------------------------------------------------------
__global__ __launch_bounds__(256) void splitw_pack_k(
    const float* __restrict__ w, ushort_t* __restrict__ hi, ushort_t* __restrict__ lo,
    int NW, int K)
{
    int i = blockIdx.x * 256 + threadIdx.x;
    if (i >= NW * K) return;
    int row = i / K, k = i % K;
    int g = row / 192, c = row % 192;
    float v = w[i];
    ushort_t hb = f2bf(v);
    size_t o = (size_t)g * K * 192 + (size_t)(k >> 4) * 3072 + (size_t)c * 16 + (k & 15);
    hi[o] = hb;
    lo[o] = f2bf(v - bf2f(hb));
}

// ---------------------------------------------------------------------------
// Split-bf16 MFMA GEMM, A-resident LDS, W packed-global depth-3 prefetch.
// EPI 0: qkv (by0 q bounce-store + qsum; by1/2 k/v transposed split).
// EPI 3: v = h + acc/(sum dsum)+bias (NO h write-back: final h is dead);
//        pool partial of v; fused LN2 + split -> bounce-store hn.
// ---------------------------------------------------------------------------
template <int EPI, int KT, int NBY>
__global__ __launch_bounds__(256) void mgemm(
    const ushort_t* __restrict__ Ah, const ushort_t* __restrict__ Al,
    const ushort_t* __restrict__ Wh, const ushort_t* __restrict__ Wl,
    const float* __restrict__ bias, float* __restrict__ dsum,
    const float* __restrict__ lng, const float* __restrict__ lnb,
    ushort_t* __restrict__ oh, ushort_t* __restrict__ ol,
    ushort_t* __restrict__ kTh, ushort_t* __restrict__ kTl,
    ushort_t* __restrict__ vTh, ushort_t* __restrict__ vTl,
    const float* __restrict__ facc, float* __restrict__ pooledp)
{
    extern __shared__ ushort_t smem[];
    constexpr int NS  = KT / 16;
    constexpr int APL = APL12;

    const int tid  = threadIdx.x;
    const int lane = tid & 63;
    const int l5   = lane >> 5;
    const int wid  = tid >> 6;
    const int wr = wid >> 1, wc = wid & 1;

    int bx, by;
    {
        int gmx = gridDim.x / NBY;
        int xx = blockIdx.x & 7, ii = blockIdx.x >> 3;
        by = ii % NBY;
        bx = xx * (gmx >> 3) + ii / NBY;
    }
    const int m0 = bx * 64;
    const int batch = m0 >> 11;

    size_t wbase = 0;
    if (EPI == 0) wbase = (size_t)by * 192 * KT;
    else if (EPI == 3) wbase = (size_t)batch * D_ * D_;
    const ushort_t* Whp = Wh + wbase;
    const ushort_t* Wlp = Wl + wbase;

    auto stageChunk = [&](int kr) {
#pragma unroll
        for (int i = 0; i < 12; ++i) {
            int c = wid + i * 4;
            int plane = c & 1, k8 = c >> 1;
            const ushort_t* ap = plane ? Al : Ah;
            const ushort_t* src = ap + (size_t)(m0 + lane) * KT + kr * 192 + k8 * 8;
            __builtin_amdgcn_global_load_lds(
                (const __attribute__((address_space(1))) void*)src,
                (__attribute__((address_space(3))) void*)(smem + plane * APL + k8 * 512),
                16, 0, 0);
        }
    };

    const int wcol = (wc * 96 + (lane & 31)) * 16 + l5 * 8;
    auto loadW = [&](int sg, bf16x8* w) {
#pragma unroll
        for (int tn = 0; tn < 3; ++tn) {
            size_t off = (size_t)sg * 3072 + wcol + tn * 512;
            w[tn * 2 + 0] = ldfrag(Whp + off);
            w[tn * 2 + 1] = ldfrag(Wlp + off);
        }
    };

    f32x16 acc[3] = {};
    const int arow = (wr * 32 + (lane & 31)) * 8;

    bf16x8 w0[6], w1[6], w2[6];
    loadW(0, w0);
    if (NS > 1) loadW(1, w1);
    if (NS > 2) loadW(2, w2);

#pragma unroll
    for (int s = 0; s < NS; ++s) {
        if ((s % 12) == 0) {
            if (s) __syncthreads();
            stageChunk(s / 12);
            __syncthreads();
        }
        bf16x8* wcur = (s % 3 == 0) ? w0 : ((s % 3 == 1) ? w1 : w2);
        int ao = ((s % 12) * 2 + l5) * 512 + arow;
        bf16x8 ah = ldfrag(smem + ao);
        bf16x8 al = ldfrag(smem + APL + ao);
#pragma unroll
        for (int tn = 0; tn < 3; ++tn) {
            acc[tn] = __builtin_amdgcn_mfma_f32_32x32x16_bf16(ah, wcur[tn * 2 + 0], acc[tn], 0, 0, 0);
            acc[tn] = __builtin_amdgcn_mfma_f32_32x32x16_bf16(ah, wcur[tn * 2 + 1], acc[tn], 0, 0, 0);
            acc[tn] = __builtin_amdgcn_mfma_f32_32x32x16_bf16(al, wcur[tn * 2 + 0], acc[tn], 0, 0, 0);
        }
        if (s + 3 < NS) loadW(s + 3, wcur);
    }

    const int cb = wc * 96 + (lane & 31);
    const int rb0 = m0 + wr * 32 + 4 * l5;
    const int rl0 = wr * 32 + 4 * l5;

    if (EPI == 0) {
        if (by == 0) {
            float qsum = 0.f;
            __syncthreads();
#pragma unroll
            for (int tn = 0; tn < 3; ++tn) {
                const int col = cb + tn * 32;
                const float bv = bias[col];
#pragma unroll
                for (int r = 0; r < 16; ++r) {
                    int rowl = rl0 + (r & 3) + 8 * (r >> 2);
                    float v = fmaxf(acc[tn][r] + bv, 0.f);
                    qsum += v;
                    ushort_t hb = f2bf(v);
                    smem[rowl * 192 + col] = hb;
                    smem[APL + rowl * 192 + col] = f2bf(v - bf2f(hb));
                }
            }
            __syncthreads();
            {
                size_t gb = (size_t)m0 * 192;
#pragma unroll
                for (int j = 0; j < 6; ++j) {
                    int idx = (tid * 6 + j) * 8;
                    *(uint4*)(oh + gb + idx) = *(const uint4*)&smem[idx];
                    *(uint4*)(ol + gb + idx) = *(const uint4*)&smem[APL + idx];
                }
            }
            float* red = (float*)(smem + 2 * APL);
            red[tid] = qsum;
            __syncthreads();
            for (int o = 128; o > 0; o >>= 1) {
                if (tid < o) red[tid] += red[tid + o];
                __syncthreads();
            }
            if (tid == 0) dsum[batch * 32 + ((m0 >> 6) & 31)] = red[0];
        } else {
            ushort_t* dsth = (by == 1) ? kTh : vTh;
            ushort_t* dstl = (by == 1) ? kTl : vTl;
            constexpr int STR = 72;
#pragma unroll
            for (int plane = 0; plane < 2; ++plane) {
                __syncthreads();
#pragma unroll
                for (int tn = 0; tn < 3; ++tn) {
                    const int col = cb + tn * 32;
                    const float bv = bias[by * 192 + col];
#pragma unroll
                    for (int r = 0; r < 16; ++r) {
                        int rowl = rl0 + (r & 3) + 8 * (r >> 2);
                        float v = acc[tn][r] + bv;
                        if (by == 1) v = fmaxf(v, 0.f);
                        ushort_t hb = f2bf(v);
                        smem[col * STR + rowl] = plane ? f2bf(v - bf2f(hb)) : hb;
                    }
                }
                __syncthreads();
                if (tid < 192) {
                    ushort_t* dst = plane ? dstl : dsth;
                    size_t gbase = ((size_t)batch * 192 + tid) * (size_t)N_ + (m0 & 2047);
#pragma unroll
                    for (int i2 = 0; i2 < 8; ++i2)
                        *(uint4*)(dst + gbase + i2 * 8) = *(const uint4*)&smem[tid * STR + i2 * 8];
                }
            }
        }
    } else if (EPI == 3) {
        float ds = 0.f;
        const float* dp = dsum + batch * 32;
#pragma unroll
        for (int j = 0; j < 32; ++j) ds += dp[j];
        const float s = 1.f / (ds + 1e-6f);
        float tsum[3] = {0.f, 0.f, 0.f};
#pragma unroll
        for (int tn = 0; tn < 3; ++tn) {
            const int col = cb + tn * 32;
            const float bv = bias[col];
#pragma unroll
            for (int r = 0; r < 16; ++r) {
                int row = rb0 + (r & 3) + 8 * (r >> 2);
                float v = facc[(size_t)row * D_ + col] + acc[tn][r] * s + bv;
                acc[tn][r] = v;                  // no h write-back (dead)
                tsum[tn] += v;
            }
        }
#pragma unroll
        for (int tn = 0; tn < 3; ++tn) {
            float t = tsum[tn];
            t += __shfl_xor(t, 32);
            if (l5 == 0) atomicAdd(&pooledp[(size_t)batch * D_ + cb + tn * 32], t);
        }
        __syncthreads();
        float* ls = (float*)(smem + 2 * APL);
        float* lq = ls + 128;
        float* lm = lq + 128;
        float* lr = lm + 64;
#pragma unroll
        for (int r = 0; r < 16; ++r) {
            float pv = acc[0][r] + acc[1][r] + acc[2][r];
            float qv = acc[0][r] * acc[0][r] + acc[1][r] * acc[1][r] + acc[2][r] * acc[2][r];
#pragma unroll
            for (int off = 1; off <= 16; off <<= 1) {
                pv += __shfl_xor(pv, off);
                qv += __shfl_xor(qv, off);
            }
            if ((lane & 31) == 0) {
                int rl = rl0 + (r & 3) + 8 * (r >> 2);
                ls[rl * 2 + wc] = pv;
                lq[rl * 2 + wc] = qv;
            }
        }
        __syncthreads();
        if (tid < 64) {
            float sv = ls[tid * 2] + ls[tid * 2 + 1];
            float qv = lq[tid * 2] + lq[tid * 2 + 1];
            float mv = sv * (1.f / D_);
            lm[tid] = mv;
            lr[tid] = rsqrtf(qv * (1.f / D_) - mv * mv + 1e-5f);
        }
        __syncthreads();
#pragma unroll
        for (int tn = 0; tn < 3; ++tn) {
            const int col = cb + tn * 32;
            const float gv = lng[col], bv2 = lnb[col];
#pragma unroll
            for (int r = 0; r < 16; ++r) {
                int rl = rl0 + (r & 3) + 8 * (r >> 2);
                float nv = (acc[tn][r] - lm[rl]) * lr[rl] * gv + bv2;
                ushort_t hb = f2bf(nv);
                smem[rl * 192 + col] = hb;
                smem[APL + rl * 192 + col] = f2bf(nv - bf2f(hb));
            }
        }
        __syncthreads();
        {
            size_t gb = (size_t)m0 * 192;
#pragma unroll
            for (int j = 0; j < 6; ++j) {
                int idx = (tid * 6 + j) * 8;
                *(uint4*)(oh + gb + idx) = *(const uint4*)&smem[idx];
                *(uint4*)(ol + gb + idx) = *(const uint4*)&smem[APL + idx];
            }
        }
    }
}

// ---------------------------------------------------------------------------
// Fused MLP, group-split, NO h materialization (final h is dead -- only the
// pool needs the MLP output sums). Block (bx,g): m_g = gelu(hn@W1_g^T+b1_g),
// partial mlp2 over K-half g, pool partials via atomicAdd (g0 adds b2 term).
// ---------------------------------------------------------------------------
__global__ __launch_bounds__(256) void fused_mlp_g(
    const ushort_t* __restrict__ Ah, const ushort_t* __restrict__ Al,
    const ushort_t* __restrict__ W1h, const ushort_t* __restrict__ W1l,
    const ushort_t* __restrict__ W2h, const ushort_t* __restrict__ W2l,
    const float* __restrict__ b1, const float* __restrict__ b2,
    float* __restrict__ pooled)
{
    extern __shared__ ushort_t smem[];

    const int tid  = threadIdx.x;
    const int lane = tid & 63;
    const int l5   = lane >> 5;
    const int wid  = tid >> 6;
    const int wr = wid >> 1, wc = wid & 1;

    int bx, g;
    {
        int gmx = gridDim.x / 2;
        int xx = blockIdx.x & 7, ii = blockIdx.x >> 3;
        g = ii & 1;
        bx = xx * (gmx >> 3) + (ii >> 1);
    }
    const int m0 = bx * 64;
    const int batch = m0 >> 11;

    // stage hn panel (K=192, both planes), padded units
#pragma unroll
    for (int i = 0; i < 12; ++i) {
        int c = wid + i * 4;
        int plane = c & 1, k8 = c >> 1;
        const ushort_t* ap = plane ? Al : Ah;
        const ushort_t* src = ap + (size_t)(m0 + lane) * 192 + k8 * 8;
        __builtin_amdgcn_global_load_lds(
            (const __attribute__((address_space(1))) void*)src,
            (__attribute__((address_space(3))) void*)(smem + plane * APAD + k8 * 520),
            16, 0, 0);
    }

    const int wcol = (wc * 96 + (lane & 31)) * 16 + l5 * 8;
    const int arow = (wr * 32 + (lane & 31)) * 8;

    auto loadWf = [&](const ushort_t* Wh, const ushort_t* Wl, int sg, bf16x8* w) {
#pragma unroll
        for (int tn = 0; tn < 3; ++tn) {
            size_t off = (size_t)sg * 3072 + wcol + tn * 512;
            w[tn * 2 + 0] = ldfrag(Wh + off);
            w[tn * 2 + 1] = ldfrag(Wl + off);
        }
    };

    const ushort_t* Wg1h = W1h + g * 36864;
    const ushort_t* Wg1l = W1l + g * 36864;

    bf16x8 w0[6], w1[6], w2[6];
    loadWf(Wg1h, Wg1l, 0, w0);
    loadWf(Wg1h, Wg1l, 1, w1);
    loadWf(Wg1h, Wg1l, 2, w2);
    __syncthreads();

    // ---- mlp1 (group g) ----
    f32x16 accm[3] = {};
#pragma unroll
    for (int s = 0; s < 12; ++s) {
        bf16x8* wcur = (s % 3 == 0) ? w0 : ((s % 3 == 1) ? w1 : w2);
        int ao = (s * 2 + l5) * 520 + arow;
        bf16x8 ah = ldfrag(smem + ao);
        bf16x8 al = ldfrag(smem + APAD + ao);
#pragma unroll
        for (int tn = 0; tn < 3; ++tn) {
            accm[tn] = __builtin_amdgcn_mfma_f32_32x32x16_bf16(ah, wcur[tn * 2 + 0], accm[tn], 0, 0, 0);
            accm[tn] = __builtin_amdgcn_mfma_f32_32x32x16_bf16(ah, wcur[tn * 2 + 1], accm[tn], 0, 0, 0);
            accm[tn] = __builtin_amdgcn_mfma_f32_32x32x16_bf16(al, wcur[tn * 2 + 0], accm[tn], 0, 0, 0);
        }
        if (s + 3 < 12) loadWf(Wg1h, Wg1l, s + 3, wcur);
    }

    // ---- gelu bounce m_g through padded LDS ----
    __syncthreads();
#pragma unroll
    for (int tn = 0; tn < 3; ++tn) {
        const int cl = wc * 96 + tn * 32 + (lane & 31);
        const float bv = b1[g * 192 + cl];
#pragma unroll
        for (int r = 0; r < 16; ++r) {
            int rowl = wr * 32 + 4 * l5 + (r & 3) + 8 * (r >> 2);
            float v = accm[tn][r] + bv;
            float gv = 0.5f * v * (1.f + erff(v * 0.70710678118654752f));
            ushort_t hb = f2bf(gv);
            int ad = (cl >> 3) * 520 + rowl * 8 + (cl & 7);
            smem[ad] = hb;
            smem[APAD + ad] = f2bf(gv - bf2f(hb));
        }
    }
    __syncthreads();

    // ---- mlp2 partial over K-half g ----
    f32x16 acco[3] = {};
    loadWf(W2h, W2l, g * 12 + 0, w0);
    loadWf(W2h, W2l, g * 12 + 1, w1);
    loadWf(W2h, W2l, g * 12 + 2, w2);
#pragma unroll
    for (int s = 0; s < 12; ++s) {
        bf16x8* wcur = (s % 3 == 0) ? w0 : ((s % 3 == 1) ? w1 : w2);
        int ao = (s * 2 + l5) * 520 + arow;
        bf16x8 ah = ldfrag(smem + ao);
        bf16x8 al = ldfrag(smem + APAD + ao);
#pragma unroll
        for (int tn = 0; tn < 3; ++tn) {
            acco[tn] = __builtin_amdgcn_mfma_f32_32x32x16_bf16(ah, wcur[tn * 2 + 0], acco[tn], 0, 0, 0);
            acco[tn] = __builtin_amdgcn_mfma_f32_32x32x16_bf16(ah, wcur[tn * 2 + 1], acco[tn], 0, 0, 0);
            acco[tn] = __builtin_amdgcn_mfma_f32_32x32x16_bf16(al, wcur[tn * 2 + 0], acco[tn], 0, 0, 0);
        }
        if (s + 3 < 12) loadWf(W2h, W2l, g * 12 + s + 3, wcur);
    }

    // ---- epilogue: pool partials only (no h writes) ----
    const int cb = wc * 96 + (lane & 31);
#pragma unroll
    for (int tn = 0; tn < 3; ++tn) {
        const int col = cb + tn * 32;
        float t = (g == 0) ? 16.f * b2[col] : 0.f;
#pragma unroll
        for (int r = 0; r < 16; ++r) t += acco[tn][r];
        t += __shfl_xor(t, 32);
        if (l5 == 0) atomicAdd(&pooled[(size_t)batch * D_ + col], t);
    }
}

// ---------------------------------------------------------------------------
// kv slab GEMM: kvslab[z][b,d,e], both operands LDS-staged, BK=32 dbuf.
// ---------------------------------------------------------------------------
__global__ __launch_bounds__(256) void mgemm_kv(
    const ushort_t* __restrict__ Ah, const ushort_t* __restrict__ Al,
    const ushort_t* __restrict__ Wh, const ushort_t* __restrict__ Wl,
    float* __restrict__ facc, size_t span)
{
    extern __shared__ ushort_t smem[];
    constexpr int BM = 64;
    constexpr int APL = BM * 32, AK = BM * 8, AELEMS = BM * 64;
    constexpr int BUFE = AELEMS + 12288;
    constexpr int ACH = 8, NCH = ACH + 24;

    const int tid  = threadIdx.x;
    const int lane = tid & 63;
    const int l5   = lane >> 5;
    const int wid  = tid >> 6;
    const int wr = wid >> 1, wc = wid & 1;
    const int bx = blockIdx.x;
    const int m0 = bx * BM;

    const size_t wbase = (size_t)(bx / 3) * 192 * (size_t)N_;
    const ushort_t* Whp = Wh + wbase;
    const ushort_t* Wlp = Wl + wbase;

    const int seg = N_ / gridDim.z;
    const int kbeg = blockIdx.z * seg, kend = kbeg + seg;

    auto stage = [&](int buf, int k0) {
        const int base = buf * BUFE;
#pragma unroll
        for (int i = 0; i < NCH / 4; ++i) {
            int c = wid + i * 4;
            const ushort_t* src;
            int dst;
            if (c < ACH) {
                int koct = c & 3, tt = c >> 2;
                int plane = tt & 1;
                const ushort_t* ap = plane ? Al : Ah;
                src = ap + (size_t)(m0 + lane) * N_ + k0 + koct * 8;
                dst = plane * APL + koct * AK;
            } else {
                int c2 = c - ACH;
                int koct = c2 & 3, tt = c2 >> 2;
                int plane = tt & 1, rb = tt >> 1;
                const ushort_t* wp = plane ? Wlp : Whp;
                src = wp + (size_t)(rb * 64 + lane) * N_ + k0 + koct * 8;
                dst = AELEMS + plane * 6144 + koct * 1536 + rb * 512;
            }
            __builtin_amdgcn_global_load_lds(
                (const __attribute__((address_space(1))) void*)src,
                (__attribute__((address_space(3))) void*)(smem + base + dst),
                16, 0, 0);
        }
    };

    f32x16 acc[3] = {};

    const int nt = (kend - kbeg) / 32;
    stage(0, kbeg);
    __syncthreads();
    int cur = 0;
    for (int t = 0; t < nt; ++t) {
        if (t + 1 < nt) stage(cur ^ 1, kbeg + (t + 1) * 32);
        const ushort_t* bb = smem + cur * BUFE;
#pragma unroll
        for (int kh = 0; kh < 2; ++kh) {
            int ao = (kh * 2 + l5) * AK + (wr * 32 + (lane & 31)) * 8;
            bf16x8 ah = ldfrag(bb + ao);
            bf16x8 al = ldfrag(bb + APL + ao);
#pragma unroll
            for (int tn = 0; tn < 3; ++tn) {
                int wo = AELEMS + (kh * 2 + l5) * 1536 + (wc * 96 + tn * 32 + (lane & 31)) * 8;
                bf16x8 wh = ldfrag(bb + wo);
                bf16x8 wl = ldfrag(bb + wo + 6144);
                acc[tn] = __builtin_amdgcn_mfma_f32_32x32x16_bf16(ah, wh, acc[tn], 0, 0, 0);
                acc[tn] = __builtin_amdgcn_mfma_f32_32x32x16_bf16(ah, wl, acc[tn], 0, 0, 0);
                acc[tn] = __builtin_amdgcn_mfma_f32_32x32x16_bf16(al, wh, acc[tn], 0, 0, 0);
            }
        }
        __syncthreads();
        cur ^= 1;
    }

    float* fz = facc + (size_t)blockIdx.z * span;
    const int cb = wc * 96 + (lane & 31);
    const int rb0 = m0 + wr * 32 + 4 * l5;
#pragma unroll
    for (int tn = 0; tn < 3; ++tn) {
        const int col = cb + tn * 32;
#pragma unroll
        for (int r = 0; r < 16; ++r) {
            int row = rb0 + (r & 3) + 8 * (r >> 2);
            fz[(size_t)row * D_ + col] = acc[tn][r];
        }
    }
}

// ---------------------------------------------------------------------------
// kv2T[b,e,d] = sum_f proj_w[e,f] * (sum_z kvslab[z][b,d,f]) -> packed split
// ---------------------------------------------------------------------------
__global__ __launch_bounds__(256) void kv2_k(
    const float* __restrict__ pw, const float* __restrict__ kvs, size_t span,
    ushort_t* __restrict__ oh, ushort_t* __restrict__ ol)
{
    __shared__ float As[16][68];
    __shared__ float Ws[16][68];
    const int tid = threadIdx.x;
    const int tx = tid & 15, ty = tid >> 4;
    const int m0 = blockIdx.x * 64;   // e
    const int n0 = blockIdx.y * 64;   // d
    const int b = blockIdx.z;
    const int lm = tid >> 2;
    const int lk = (tid & 3) * 4;

    float acc[4][4] = {};
    for (int k0 = 0; k0 < D_; k0 += 16) {
        float4 av = *(const float4*)(pw + (size_t)(m0 + lm) * D_ + k0 + lk);
        As[lk + 0][lm] = av.x; As[lk + 1][lm] = av.y;
        As[lk + 2][lm] = av.z; As[lk + 3][lm] = av.w;
        const float* base = kvs + (size_t)b * D_ * D_ + (size_t)(n0 + lm) * D_ + k0 + lk;
        float4 wv = {0.f, 0.f, 0.f, 0.f};
#pragma unroll
        for (int z = 0; z < 8; ++z) {
            float4 t = *(const float4*)(base + z * span);
            wv.x += t.x; wv.y += t.y; wv.z += t.z; wv.w += t.w;
        }
        Ws[lk + 0][lm] = wv.x; Ws[lk + 1][lm] = wv.y;
        Ws[lk + 2][lm] = wv.z; Ws[lk + 3][lm] = wv.w;
        __syncthreads();
#pragma unroll
        for (int kk = 0; kk < 16; ++kk) {
            float4 a4 = *(const float4*)&As[kk][ty * 4];
            float4 w4 = *(const float4*)&Ws[kk][tx * 4];
            float a[4] = {a4.x, a4.y, a4.z, a4.w};
            float w[4] = {w4.x, w4.y, w4.z, w4.w};
#pragma unroll
            for (int i = 0; i < 4; ++i)
#pragma unroll
                for (int j = 0; j < 4; ++j) acc[i][j] += a[i] * w[j];
        }
        __syncthreads();
    }
    const int d0 = n0 + tx * 4;
#pragma unroll
    for (int i = 0; i < 4; ++i) {
        ushort_t hb[4], lb[4];
#pragma unroll
        for (int j = 0; j < 4; ++j) {
            float v = acc[i][j];
            hb[j] = f2bf(v);
            lb[j] = f2bf(v - bf2f(hb[j]));
        }
        const int e = m0 + ty * 4 + i;
        size_t off = (size_t)b * D_ * D_ + ((size_t)(d0 >> 4) * 192 + e) * 16 + (d0 & 15);
        *(uint2*)&oh[off] = make_uint2((unsigned)hb[0] | ((unsigned)hb[1] << 16),
                                       (unsigned)hb[2] | ((unsigned)hb[3] << 16));
        *(uint2*)&ol[off] = make_uint2((unsigned)lb[0] | ((unsigned)lb[1] << 16),
                                       (unsigned)lb[2] | ((unsigned)lb[3] << 16));
    }
}

// ---------------------------------------------------------------------------
__global__ __launch_bounds__(192) void head_k(
    const float* __restrict__ pooled, const float* __restrict__ hw,
    const float* __restrict__ hb, float* __restrict__ out)
{
    const int b = blockIdx.x, d = threadIdx.x;
    __shared__ float p[D_];
    p[d] = pooled[(size_t)b * D_ + d] * (1.f / N_);
    __syncthreads();
    if (d < NC_) {
        float acc = hb[d];
        for (int e = 0; e < D_; ++e) acc += p[e] * hw[d * D_ + e];
        out[b * NC_ + d] = acc;
    }
}

// ---------------------------------------------------------------------------
extern "C" void kernel_launch(void* const* d_in, const int* in_sizes, int n_in,
                              void* d_out, int out_size, void* d_ws, size_t ws_size,
                              hipStream_t stream) {
    (void)in_sizes; (void)n_in; (void)out_size;

    const float* x      = (const float*)d_in[0];
    const float* conv_w = (const float*)d_in[1];
    const float* conv_b = (const float*)d_in[2];
    const float* pos    = (const float*)d_in[3];
    const float* qkv_w  = (const float*)d_in[4];
    const float* qkv_b  = (const float*)d_in[5];
    const float* proj_w = (const float*)d_in[6];
    const float* proj_b = (const float*)d_in[7];
    const float* ln1_g  = (const float*)d_in[8];
    const float* ln1_b  = (const float*)d_in[9];
    const float* mlp_w1 = (const float*)d_in[10];
    const float* mlp_b1 = (const float*)d_in[11];
    const float* mlp_w2 = (const float*)d_in[12];
    const float* mlp_b2 = (const float*)d_in[13];
    const float* ln2_g  = (const float*)d_in[14];
    const float* ln2_b  = (const float*)d_in[15];
    const float* head_w = (const float*)d_in[16];
    const float* head_b = (const float*)d_in[17];
    float* out = (float*)d_out;

    const size_t perB =
        (size_t)N_ * D_ * 4 +            // h
        (size_t)N_ * D_ * 2 * 2 +        // hn hi+lo (aliased by kv slabs)
        (size_t)N_ * D_ * 2 * 2 +        // q hi+lo
        (size_t)N_ * D_ * 2 * 4 +        // kT,vT hi+lo
        (size_t)D_ * D_ * 2 * 2 +        // kv2t hi+lo (packed)
        16384;
    const size_t fixedW = 2ull * (576 * 192 + 384 * 192 + 192 * 384) * 2 + 65536;
    int BC = B_;
    while (BC > 1 && fixedW + (size_t)BC * perB > ws_size) BC >>= 1;
    const int nchunks = B_ / BC;
    const size_t rows = (size_t)BC * N_;

    char* p = (char*)d_ws;
    auto alloc = [&](size_t bytes) -> char* {
        char* r = p;
        p += (bytes + 255) & ~(size_t)255;
        return r;
    };
    ushort_t* qw_hi = (ushort_t*)alloc(576 * 192 * 2);
    ushort_t* qw_lo = (ushort_t*)alloc(576 * 192 * 2);
    ushort_t* w1_hi = (ushort_t*)alloc(384 * 192 * 2);
    ushort_t* w1_lo = (ushort_t*)alloc(384 * 192 * 2);
    ushort_t* w2_hi = (ushort_t*)alloc(192 * 384 * 2);
    ushort_t* w2_lo = (ushort_t*)alloc(192 * 384 * 2);

    const size_t szPl = rows * D_ * 2;
    float*    h      = (float*)alloc(rows * D_ * 4);
    ushort_t* hn_hi  = (ushort_t*)alloc(szPl);
    ushort_t* hn_lo  = (ushort_t*)alloc(szPl);
    ushort_t* q_hi   = (ushort_t*)alloc(szPl);
    ushort_t* q_lo   = (ushort_t*)alloc(szPl);
    ushort_t* kT_hi  = (ushort_t*)alloc(szPl);
    ushort_t* kT_lo  = (ushort_t*)alloc(szPl);
    ushort_t* vT_hi  = (ushort_t*)alloc(szPl);
    ushort_t* vT_lo  = (ushort_t*)alloc(szPl);
    ushort_t* kv2t_h = (ushort_t*)alloc((size_t)BC * D_ * D_ * 2);
    ushort_t* kv2t_l = (ushort_t*)alloc((size_t)BC * D_ * D_ * 2);
    float*    dsum   = (float*)alloc((size_t)BC * 32 * 4);
    float*    pooled = (float*)alloc((size_t)BC * D_ * 4);
    float*    kvs    = (float*)hn_hi;       // 8 kv slabs alias hn (dead there)
    const size_t kvspan = (size_t)BC * D_ * D_;

    splitw_pack_k<<<(576 * 192 + 255) / 256, 256, 0, stream>>>(qkv_w, qw_hi, qw_lo, 576, 192);
    splitw_pack_k<<<(384 * 192 + 255) / 256, 256, 0, stream>>>(mlp_w1, w1_hi, w1_lo, 384, 192);
    splitw_pack_k<<<(192 * 384 + 255) / 256, 256, 0, stream>>>(mlp_w2, w2_hi, w2_lo, 192, 384);

    const int gm = (int)(rows / 64);
    const size_t SHQ = 50688;                              // mgemm planes + scratch
    const size_t SHG = (size_t)APAD * 2 * 2;               // fused_mlp_g padded planes
    const size_t SH4 = (size_t)(64 * 64 + 12288) * 2 * 2;  // kv dbuf

    for (int ch = 0; ch < nchunks; ++ch) {
        const int b0 = ch * BC;
        const float* xc = x + (size_t)b0 * C_ * N_;

        hipMemsetAsync(pooled, 0, (size_t)BC * D_ * 4, stream);

        // 1. conv + pos + LN1 + split
        conv_ln_k<<<dim3(N_ / 64, BC), 192, 0, stream>>>(
            xc, conv_w, conv_b, pos, ln1_g, ln1_b, h, hn_hi, hn_lo);
        // 2. qkv: q split + qsum slots; k,v transposed split
        mgemm<0, 192, 3><<<gm * 3, 256, SHQ, stream>>>(
            hn_hi, hn_lo, qw_hi, qw_lo, qkv_b, dsum, nullptr, nullptr,
            q_hi, q_lo, kT_hi, kT_lo, vT_hi, vT_lo, nullptr, nullptr);
        // 3. kv z-slabs = k^T v (K-split 8, plain stores into hn-aliased slabs)
        mgemm_kv<<<dim3(BC * 3, 1, 8), 256, SH4, stream>>>(
            kT_hi, kT_lo, vT_hi, vT_lo, kvs, kvspan);
        // 4. kv2T = proj_w @ (sum slabs)^T -> packed split
        kv2_k<<<dim3(3, 3, BC), 256, 0, stream>>>(proj_w, kvs, kvspan, kv2t_h, kv2t_l);
        // 5. v = h + (q@kv2)/denom + proj_b; pool partial of v; LN2+split -> hn
        mgemm<3, 192, 1><<<gm, 256, SHQ, stream>>>(
            q_hi, q_lo, kv2t_h, kv2t_l, proj_b, dsum, ln2_g, ln2_b,
            hn_hi, hn_lo, nullptr, nullptr, nullptr, nullptr, h, pooled);
        // 6. fused MLP group-split: pool += mlp partial sums (no h writes)
        fused_mlp_g<<<gm * 2, 256, SHG, stream>>>(
            hn_hi, hn_lo, w1_hi, w1_lo, w2_hi, w2_lo, mlp_b1, mlp_b2, pooled);
        // 7. head
        head_k<<<BC, 192, 0, stream>>>(pooled, head_w, head_b, out + (size_t)b0 * NC_);
    }
}

// Round 18
// 1442.458 us; speedup vs baseline: 1.0298x; 1.0106x over previous
//
#include <hip/hip_runtime.h>
#include <cmath>

#define B_   128
#define C_   9
#define N_   2048
#define D_   192
#define H_   384
#define NC_  18

typedef unsigned short ushort_t;
typedef __attribute__((ext_vector_type(8))) __bf16 bf16x8;
typedef __attribute__((ext_vector_type(8))) short short8;
typedef __attribute__((ext_vector_type(16))) float f32x16;

__device__ __forceinline__ ushort_t f2bf(float x) {
    unsigned u = __float_as_uint(x);
    return (ushort_t)((u + 0x7fffu + ((u >> 16) & 1u)) >> 16);
}
__device__ __forceinline__ float bf2f(ushort_t h) {
    return __uint_as_float(((unsigned)h) << 16);
}
__device__ __forceinline__ bf16x8 ldfrag(const ushort_t* p) {
    short8 s = *(const short8*)p;
    return __builtin_bit_cast(bf16x8, s);
}

#define APL12 12288   // mgemm linear plane stride (24 k8 * 64 * 8)
#define APAD  12480   // fused_mlp padded plane stride (24 units * 520)
// blocked kT/vT layout: [batch][nchunk(32)][192 rows][64 n] (ushorts)
#define KVCH  12288   // 192*64 elems per n-chunk
#define KVBATCH 393216 // 32*KVCH per batch

// ---------------------------------------------------------------------------
// conv1d(C->D,k=3,pad=1) + pos_embed + LayerNorm1 + hi/lo split, fully fused.
// ---------------------------------------------------------------------------
__global__ __launch_bounds__(192) void conv_ln_k(
    const float* __restrict__ x, const float* __restrict__ w,
    const float* __restrict__ cb, const float* __restrict__ pos,
    const float* __restrict__ lng, const float* __restrict__ lnb,
    float* __restrict__ h, ushort_t* __restrict__ oh, ushort_t* __restrict__ ol)
{
    const int n0 = blockIdx.x * 64;
    const int b  = blockIdx.y;
    const int d  = threadIdx.x;

    __shared__ float xs[C_][66];
    __shared__ float tile[64][193];
    __shared__ float ps[64][3], pq[64][3];
    __shared__ float mm[64], rr[64];

    for (int e = threadIdx.x; e < C_ * 66; e += 192) {
        int c = e / 66, i = e % 66;
        int n = n0 - 1 + i;
        xs[c][i] = (n >= 0 && n < N_) ? x[((size_t)b * C_ + c) * N_ + n] : 0.f;
    }
    float wr[C_][3];
#pragma unroll
    for (int c = 0; c < C_; ++c)
#pragma unroll
        for (int t = 0; t < 3; ++t) wr[c][t] = w[(d * C_ + c) * 3 + t];
    const float bias = cb[d];
    __syncthreads();

    for (int i = 0; i < 64; ++i) {
        float acc = bias + pos[(size_t)(n0 + i) * D_ + d];
#pragma unroll
        for (int c = 0; c < C_; ++c)
#pragma unroll
            for (int t = 0; t < 3; ++t) acc += xs[c][i + t] * wr[c][t];
        tile[i][d] = acc;
    }
    __syncthreads();

    {
        int row = threadIdx.x & 63, part = threadIdx.x >> 6;
        float s = 0.f, q = 0.f;
        const float* tr = &tile[row][part * 64];
#pragma unroll 8
        for (int j = 0; j < 64; ++j) { float v = tr[j]; s += v; q += v * v; }
        ps[row][part] = s; pq[row][part] = q;
    }
    __syncthreads();
    if (threadIdx.x < 64) {
        int r = threadIdx.x;
        float s = ps[r][0] + ps[r][1] + ps[r][2];
        float q = pq[r][0] + pq[r][1] + pq[r][2];
        float m = s * (1.f / D_);
        mm[r] = m;
        rr[r] = rsqrtf(q * (1.f / D_) - m * m + 1e-5f);
    }
    __syncthreads();
    {
        const float gd = lng[d], bd = lnb[d];
        for (int i = 0; i < 64; ++i) {
            float v = tile[i][d];
            size_t idx = ((size_t)b * N_ + n0 + i) * D_ + d;
            h[idx] = v;
            float nv = (v - mm[i]) * rr[i] * gd + bd;
            ushort_t hb = f2bf(nv);
            oh[idx] = hb;
            ol[idx] = f2bf(nv - bf2f(hb));
        }
    }
}

// ---------------------------------------------------------------------------
// split f32 weights -> hi/lo bf16 planes in MFMA fragment-packed layout
// ---------------------------------------------------------------------------
__global__ __launch_bounds__(256) void splitw_pack_k(
    const float* __restrict__ w, ushort_t* __restrict__ hi, ushort_t* __restrict__ lo,
    int NW, int K)
{
    int i = blockIdx.x * 256 + threadIdx.x;
    if (i >= NW * K) return;
    int row = i / K, k = i % K;
    int g = row / 192, c = row % 192;
    float v = w[i];
    ushort_t hb = f2bf(v);
    size_t o = (size_t)g * K * 192 + (size_t)(k >> 4) * 3072 + (size_t)c * 16 + (k & 15);
    hi[o] = hb;
    lo[o] = f2bf(v - bf2f(hb));
}

// ---------------------------------------------------------------------------
// Split-bf16 MFMA GEMM, A-resident LDS, W packed-global depth-3 prefetch.
// EPI 0: qkv (by0 q bounce-store + qsum; by1/2 k/v -> BLOCKED transposed
//        layout [batch][nchunk][192][64], fully contiguous 24.5KB stores).
// EPI 3: v = h + acc/(sum dsum)+bias (no h write-back: final h is dead);
//        pool partial of v; fused LN2 + split -> bounce-store hn.
// ---------------------------------------------------------------------------
template <int EPI, int KT, int NBY>
__global__ __launch_bounds__(256) void mgemm(
    const ushort_t* __restrict__ Ah, const ushort_t* __restrict__ Al,
    const ushort_t* __restrict__ Wh, const ushort_t* __restrict__ Wl,
    const float* __restrict__ bias, float* __restrict__ dsum,
    const float* __restrict__ lng, const float* __restrict__ lnb,
    ushort_t* __restrict__ oh, ushort_t* __restrict__ ol,
    ushort_t* __restrict__ kTh, ushort_t* __restrict__ kTl,
    ushort_t* __restrict__ vTh, ushort_t* __restrict__ vTl,
    const float* __restrict__ facc, float* __restrict__ pooledp)
{
    extern __shared__ ushort_t smem[];
    constexpr int NS  = KT / 16;
    constexpr int APL = APL12;

    const int tid  = threadIdx.x;
    const int lane = tid & 63;
    const int l5   = lane >> 5;
    const int wid  = tid >> 6;
    const int wr = wid >> 1, wc = wid & 1;

    int bx, by;
    {
        int gmx = gridDim.x / NBY;
        int xx = blockIdx.x & 7, ii = blockIdx.x >> 3;
        by = ii % NBY;
        bx = xx * (gmx >> 3) + ii / NBY;
    }
    const int m0 = bx * 64;
    const int batch = m0 >> 11;

    size_t wbase = 0;
    if (EPI == 0) wbase = (size_t)by * 192 * KT;
    else if (EPI == 3) wbase = (size_t)batch * D_ * D_;
    const ushort_t* Whp = Wh + wbase;
    const ushort_t* Wlp = Wl + wbase;

    auto stageChunk = [&](int kr) {
#pragma unroll
        for (int i = 0; i < 12; ++i) {
            int c = wid + i * 4;
            int plane = c & 1, k8 = c >> 1;
            const ushort_t* ap = plane ? Al : Ah;
            const ushort_t* src = ap + (size_t)(m0 + lane) * KT + kr * 192 + k8 * 8;
            __builtin_amdgcn_global_load_lds(
                (const __attribute__((address_space(1))) void*)src,
                (__attribute__((address_space(3))) void*)(smem + plane * APL + k8 * 512),
                16, 0, 0);
        }
    };

    const int wcol = (wc * 96 + (lane & 31)) * 16 + l5 * 8;
    auto loadW = [&](int sg, bf16x8* w) {
#pragma unroll
        for (int tn = 0; tn < 3; ++tn) {
            size_t off = (size_t)sg * 3072 + wcol + tn * 512;
            w[tn * 2 + 0] = ldfrag(Whp + off);
            w[tn * 2 + 1] = ldfrag(Wlp + off);
        }
    };

    f32x16 acc[3] = {};
    const int arow = (wr * 32 + (lane & 31)) * 8;

    bf16x8 w0[6], w1[6], w2[6];
    loadW(0, w0);
    if (NS > 1) loadW(1, w1);
    if (NS > 2) loadW(2, w2);

#pragma unroll
    for (int s = 0; s < NS; ++s) {
        if ((s % 12) == 0) {
            if (s) __syncthreads();
            stageChunk(s / 12);
            __syncthreads();
        }
        bf16x8* wcur = (s % 3 == 0) ? w0 : ((s % 3 == 1) ? w1 : w2);
        int ao = ((s % 12) * 2 + l5) * 512 + arow;
        bf16x8 ah = ldfrag(smem + ao);
        bf16x8 al = ldfrag(smem + APL + ao);
#pragma unroll
        for (int tn = 0; tn < 3; ++tn) {
            acc[tn] = __builtin_amdgcn_mfma_f32_32x32x16_bf16(ah, wcur[tn * 2 + 0], acc[tn], 0, 0, 0);
            acc[tn] = __builtin_amdgcn_mfma_f32_32x32x16_bf16(ah, wcur[tn * 2 + 1], acc[tn], 0, 0, 0);
            acc[tn] = __builtin_amdgcn_mfma_f32_32x32x16_bf16(al, wcur[tn * 2 + 0], acc[tn], 0, 0, 0);
        }
        if (s + 3 < NS) loadW(s + 3, wcur);
    }

    const int cb = wc * 96 + (lane & 31);
    const int rb0 = m0 + wr * 32 + 4 * l5;
    const int rl0 = wr * 32 + 4 * l5;

    if (EPI == 0) {
        if (by == 0) {
            float qsum = 0.f;
            __syncthreads();
#pragma unroll
            for (int tn = 0; tn < 3; ++tn) {
                const int col = cb + tn * 32;
                const float bv = bias[col];
#pragma unroll
                for (int r = 0; r < 16; ++r) {
                    int rowl = rl0 + (r & 3) + 8 * (r >> 2);
                    float v = fmaxf(acc[tn][r] + bv, 0.f);
                    qsum += v;
                    ushort_t hb = f2bf(v);
                    smem[rowl * 192 + col] = hb;
                    smem[APL + rowl * 192 + col] = f2bf(v - bf2f(hb));
                }
            }
            __syncthreads();
            {
                size_t gb = (size_t)m0 * 192;
#pragma unroll
                for (int j = 0; j < 6; ++j) {
                    int idx = (tid * 6 + j) * 8;
                    *(uint4*)(oh + gb + idx) = *(const uint4*)&smem[idx];
                    *(uint4*)(ol + gb + idx) = *(const uint4*)&smem[APL + idx];
                }
            }
            float* red = (float*)(smem + 2 * APL);
            red[tid] = qsum;
            __syncthreads();
            for (int o = 128; o > 0; o >>= 1) {
                if (tid < o) red[tid] += red[tid + o];
                __syncthreads();
            }
            if (tid == 0) dsum[batch * 32 + ((m0 >> 6) & 31)] = red[0];
        } else {
            ushort_t* dsth = (by == 1) ? kTh : vTh;
            ushort_t* dstl = (by == 1) ? kTl : vTl;
            constexpr int STR = 72;
#pragma unroll
            for (int plane = 0; plane < 2; ++plane) {
                __syncthreads();
#pragma unroll
                for (int tn = 0; tn < 3; ++tn) {
                    const int col = cb + tn * 32;
                    const float bv = bias[by * 192 + col];
#pragma unroll
                    for (int r = 0; r < 16; ++r) {
                        int rowl = rl0 + (r & 3) + 8 * (r >> 2);
                        float v = acc[tn][r] + bv;
                        if (by == 1) v = fmaxf(v, 0.f);
                        ushort_t hb = f2bf(v);
                        smem[col * STR + rowl] = plane ? f2bf(v - bf2f(hb)) : hb;
                    }
                }
                __syncthreads();
                if (tid < 192) {
                    ushort_t* dst = plane ? dstl : dsth;
                    // blocked layout: fully contiguous 24.5KB per (block, plane)
                    size_t gbase = (size_t)batch * KVBATCH
                                 + (size_t)((m0 >> 6) & 31) * KVCH + (size_t)tid * 64;
#pragma unroll
                    for (int i2 = 0; i2 < 8; ++i2)
                        *(uint4*)(dst + gbase + i2 * 8) = *(const uint4*)&smem[tid * STR + i2 * 8];
                }
            }
        }
    } else if (EPI == 3) {
        float ds = 0.f;
        const float* dp = dsum + batch * 32;
#pragma unroll
        for (int j = 0; j < 32; ++j) ds += dp[j];
        const float s = 1.f / (ds + 1e-6f);
        float tsum[3] = {0.f, 0.f, 0.f};
#pragma unroll
        for (int tn = 0; tn < 3; ++tn) {
            const int col = cb + tn * 32;
            const float bv = bias[col];
#pragma unroll
            for (int r = 0; r < 16; ++r) {
                int row = rb0 + (r & 3) + 8 * (r >> 2);
                float v = facc[(size_t)row * D_ + col] + acc[tn][r] * s + bv;
                acc[tn][r] = v;
                tsum[tn] += v;
            }
        }
#pragma unroll
        for (int tn = 0; tn < 3; ++tn) {
            float t = tsum[tn];
            t += __shfl_xor(t, 32);
            if (l5 == 0) atomicAdd(&pooledp[(size_t)batch * D_ + cb + tn * 32], t);
        }
        __syncthreads();
        float* ls = (float*)(smem + 2 * APL);
        float* lq = ls + 128;
        float* lm = lq + 128;
        float* lr = lm + 64;
#pragma unroll
        for (int r = 0; r < 16; ++r) {
            float pv = acc[0][r] + acc[1][r] + acc[2][r];
            float qv = acc[0][r] * acc[0][r] + acc[1][r] * acc[1][r] + acc[2][r] * acc[2][r];
#pragma unroll
            for (int off = 1; off <= 16; off <<= 1) {
                pv += __shfl_xor(pv, off);
                qv += __shfl_xor(qv, off);
            }
            if ((lane & 31) == 0) {
                int rl = rl0 + (r & 3) + 8 * (r >> 2);
                ls[rl * 2 + wc] = pv;
                lq[rl * 2 + wc] = qv;
            }
        }
        __syncthreads();
        if (tid < 64) {
            float sv = ls[tid * 2] + ls[tid * 2 + 1];
            float qv = lq[tid * 2] + lq[tid * 2 + 1];
            float mv = sv * (1.f / D_);
            lm[tid] = mv;
            lr[tid] = rsqrtf(qv * (1.f / D_) - mv * mv + 1e-5f);
        }
        __syncthreads();
#pragma unroll
        for (int tn = 0; tn < 3; ++tn) {
            const int col = cb + tn * 32;
            const float gv = lng[col], bv2 = lnb[col];
#pragma unroll
            for (int r = 0; r < 16; ++r) {
                int rl = rl0 + (r & 3) + 8 * (r >> 2);
                float nv = (acc[tn][r] - lm[rl]) * lr[rl] * gv + bv2;
                ushort_t hb = f2bf(nv);
                smem[rl * 192 + col] = hb;
                smem[APL + rl * 192 + col] = f2bf(nv - bf2f(hb));
            }
        }
        __syncthreads();
        {
            size_t gb = (size_t)m0 * 192;
#pragma unroll
            for (int j = 0; j < 6; ++j) {
                int idx = (tid * 6 + j) * 8;
                *(uint4*)(oh + gb + idx) = *(const uint4*)&smem[idx];
                *(uint4*)(ol + gb + idx) = *(const uint4*)&smem[APL + idx];
            }
        }
    }
}

// ---------------------------------------------------------------------------
// Fused MLP, group-split, no h materialization. Block (bx,g):
// m_g = gelu(hn@W1_g^T+b1_g); partial mlp2 over K-half g; pool atomics.
// ---------------------------------------------------------------------------
__global__ __launch_bounds__(256) void fused_mlp_g(
    const ushort_t* __restrict__ Ah, const ushort_t* __restrict__ Al,
    const ushort_t* __restrict__ W1h, const ushort_t* __restrict__ W1l,
    const ushort_t* __restrict__ W2h, const ushort_t* __restrict__ W2l,
    const float* __restrict__ b1, const float* __restrict__ b2,
    float* __restrict__ pooled)
{
    extern __shared__ ushort_t smem[];

    const int tid  = threadIdx.x;
    const int lane = tid & 63;
    const int l5   = lane >> 5;
    const int wid  = tid >> 6;
    const int wr = wid >> 1, wc = wid & 1;

    int bx, g;
    {
        int gmx = gridDim.x / 2;
        int xx = blockIdx.x & 7, ii = blockIdx.x >> 3;
        g = ii & 1;
        bx = xx * (gmx >> 3) + (ii >> 1);
    }
    const int m0 = bx * 64;
    const int batch = m0 >> 11;

    // stage hn panel (K=192, both planes), padded units
#pragma unroll
    for (int i = 0; i < 12; ++i) {
        int c = wid + i * 4;
        int plane = c & 1, k8 = c >> 1;
        const ushort_t* ap = plane ? Al : Ah;
        const ushort_t* src = ap + (size_t)(m0 + lane) * 192 + k8 * 8;
        __builtin_amdgcn_global_load_lds(
            (const __attribute__((address_space(1))) void*)src,
            (__attribute__((address_space(3))) void*)(smem + plane * APAD + k8 * 520),
            16, 0, 0);
    }

    const int wcol = (wc * 96 + (lane & 31)) * 16 + l5 * 8;
    const int arow = (wr * 32 + (lane & 31)) * 8;

    auto loadWf = [&](const ushort_t* Wh, const ushort_t* Wl, int sg, bf16x8* w) {
#pragma unroll
        for (int tn = 0; tn < 3; ++tn) {
            size_t off = (size_t)sg * 3072 + wcol + tn * 512;
            w[tn * 2 + 0] = ldfrag(Wh + off);
            w[tn * 2 + 1] = ldfrag(Wl + off);
        }
    };

    const ushort_t* Wg1h = W1h + g * 36864;
    const ushort_t* Wg1l = W1l + g * 36864;

    bf16x8 w0[6], w1[6], w2[6];
    loadWf(Wg1h, Wg1l, 0, w0);
    loadWf(Wg1h, Wg1l, 1, w1);
    loadWf(Wg1h, Wg1l, 2, w2);
    __syncthreads();

    // ---- mlp1 (group g) ----
    f32x16 accm[3] = {};
#pragma unroll
    for (int s = 0; s < 12; ++s) {
        bf16x8* wcur = (s % 3 == 0) ? w0 : ((s % 3 == 1) ? w1 : w2);
        int ao = (s * 2 + l5) * 520 + arow;
        bf16x8 ah = ldfrag(smem + ao);
        bf16x8 al = ldfrag(smem + APAD + ao);
#pragma unroll
        for (int tn = 0; tn < 3; ++tn) {
            accm[tn] = __builtin_amdgcn_mfma_f32_32x32x16_bf16(ah, wcur[tn * 2 + 0], accm[tn], 0, 0, 0);
            accm[tn] = __builtin_amdgcn_mfma_f32_32x32x16_bf16(ah, wcur[tn * 2 + 1], accm[tn], 0, 0, 0);
            accm[tn] = __builtin_amdgcn_mfma_f32_32x32x16_bf16(al, wcur[tn * 2 + 0], accm[tn], 0, 0, 0);
        }
        if (s + 3 < 12) loadWf(Wg1h, Wg1l, s + 3, wcur);
    }

    // ---- gelu bounce m_g through padded LDS ----
    __syncthreads();
#pragma unroll
    for (int tn = 0; tn < 3; ++tn) {
        const int cl = wc * 96 + tn * 32 + (lane & 31);
        const float bv = b1[g * 192 + cl];
#pragma unroll
        for (int r = 0; r < 16; ++r) {
            int rowl = wr * 32 + 4 * l5 + (r & 3) + 8 * (r >> 2);
            float v = accm[tn][r] + bv;
            float gv = 0.5f * v * (1.f + erff(v * 0.70710678118654752f));
            ushort_t hb = f2bf(gv);
            int ad = (cl >> 3) * 520 + rowl * 8 + (cl & 7);
            smem[ad] = hb;
            smem[APAD + ad] = f2bf(gv - bf2f(hb));
        }
    }
    __syncthreads();

    // ---- mlp2 partial over K-half g ----
    f32x16 acco[3] = {};
    loadWf(W2h, W2l, g * 12 + 0, w0);
    loadWf(W2h, W2l, g * 12 + 1, w1);
    loadWf(W2h, W2l, g * 12 + 2, w2);
#pragma unroll
    for (int s = 0; s < 12; ++s) {
        bf16x8* wcur = (s % 3 == 0) ? w0 : ((s % 3 == 1) ? w1 : w2);
        int ao = (s * 2 + l5) * 520 + arow;
        bf16x8 ah = ldfrag(smem + ao);
        bf16x8 al = ldfrag(smem + APAD + ao);
#pragma unroll
        for (int tn = 0; tn < 3; ++tn) {
            acco[tn] = __builtin_amdgcn_mfma_f32_32x32x16_bf16(ah, wcur[tn * 2 + 0], acco[tn], 0, 0, 0);
            acco[tn] = __builtin_amdgcn_mfma_f32_32x32x16_bf16(ah, wcur[tn * 2 + 1], acco[tn], 0, 0, 0);
            acco[tn] = __builtin_amdgcn_mfma_f32_32x32x16_bf16(al, wcur[tn * 2 + 0], acco[tn], 0, 0, 0);
        }
        if (s + 3 < 12) loadWf(W2h, W2l, g * 12 + s + 3, wcur);
    }

    // ---- epilogue: pool partials only (no h writes) ----
    const int cb = wc * 96 + (lane & 31);
#pragma unroll
    for (int tn = 0; tn < 3; ++tn) {
        const int col = cb + tn * 32;
        float t = (g == 0) ? 16.f * b2[col] : 0.f;
#pragma unroll
        for (int r = 0; r < 16; ++r) t += acco[tn][r];
        t += __shfl_xor(t, 32);
        if (l5 == 0) atomicAdd(&pooled[(size_t)batch * D_ + col], t);
    }
}

// ---------------------------------------------------------------------------
// kv slab GEMM: kvslab[z][b,d,e], operands in BLOCKED kT/vT layout, BK=32 dbuf.
// ---------------------------------------------------------------------------
__global__ __launch_bounds__(256) void mgemm_kv(
    const ushort_t* __restrict__ Ah, const ushort_t* __restrict__ Al,
    const ushort_t* __restrict__ Wh, const ushort_t* __restrict__ Wl,
    float* __restrict__ facc, size_t span)
{
    extern __shared__ ushort_t smem[];
    constexpr int BM = 64;
    constexpr int APL = BM * 32, AK = BM * 8, AELEMS = BM * 64;
    constexpr int BUFE = AELEMS + 12288;
    constexpr int ACH = 8, NCH = ACH + 24;

    const int tid  = threadIdx.x;
    const int lane = tid & 63;
    const int l5   = lane >> 5;
    const int wid  = tid >> 6;
    const int wr = wid >> 1, wc = wid & 1;
    const int bx = blockIdx.x;
    const int m0 = bx * BM;
    const int batch = bx / 3;
    const int drow = (bx % 3) * 64;
    (void)m0;

    const int seg = N_ / gridDim.z;
    const int kbeg = blockIdx.z * seg, kend = kbeg + seg;

    auto stage = [&](int buf, int k0) {
        const int base = buf * BUFE;
#pragma unroll
        for (int i = 0; i < NCH / 4; ++i) {
            int c = wid + i * 4;
            const ushort_t* src;
            int dst;
            if (c < ACH) {
                int koct = c & 3, tt = c >> 2;
                int plane = tt & 1;
                const ushort_t* ap = plane ? Al : Ah;
                int n = k0 + koct * 8;
                src = ap + (size_t)batch * KVBATCH + (size_t)(n >> 6) * KVCH
                         + (size_t)(drow + lane) * 64 + (n & 63);
                dst = plane * APL + koct * AK;
            } else {
                int c2 = c - ACH;
                int koct = c2 & 3, tt = c2 >> 2;
                int plane = tt & 1, rb = tt >> 1;
                const ushort_t* wp = plane ? Wl : Wh;
                int n = k0 + koct * 8;
                src = wp + (size_t)batch * KVBATCH + (size_t)(n >> 6) * KVCH
                         + (size_t)(rb * 64 + lane) * 64 + (n & 63);
                dst = AELEMS + plane * 6144 + koct * 1536 + rb * 512;
            }
            __builtin_amdgcn_global_load_lds(
                (const __attribute__((address_space(1))) void*)src,
                (__attribute__((address_space(3))) void*)(smem + base + dst),
                16, 0, 0);
        }
    };

    f32x16 acc[3] = {};

    const int nt = (kend - kbeg) / 32;
    stage(0, kbeg);
    __syncthreads();
    int cur = 0;
    for (int t = 0; t < nt; ++t) {
        if (t + 1 < nt) stage(cur ^ 1, kbeg + (t + 1) * 32);
        const ushort_t* bb = smem + cur * BUFE;
#pragma unroll
        for (int kh = 0; kh < 2; ++kh) {
            int ao = (kh * 2 + l5) * AK + (wr * 32 + (lane & 31)) * 8;
            bf16x8 ah = ldfrag(bb + ao);
            bf16x8 al = ldfrag(bb + APL + ao);
#pragma unroll
            for (int tn = 0; tn < 3; ++tn) {
                int wo = AELEMS + (kh * 2 + l5) * 1536 + (wc * 96 + tn * 32 + (lane & 31)) * 8;
                bf16x8 wh = ldfrag(bb + wo);
                bf16x8 wl = ldfrag(bb + wo + 6144);
                acc[tn] = __builtin_amdgcn_mfma_f32_32x32x16_bf16(ah, wh, acc[tn], 0, 0, 0);
                acc[tn] = __builtin_amdgcn_mfma_f32_32x32x16_bf16(ah, wl, acc[tn], 0, 0, 0);
                acc[tn] = __builtin_amdgcn_mfma_f32_32x32x16_bf16(al, wh, acc[tn], 0, 0, 0);
            }
        }
        __syncthreads();
        cur ^= 1;
    }

    float* fz = facc + (size_t)blockIdx.z * span;
    const int cb = wc * 96 + (lane & 31);
    const int rb0 = bx * BM + wr * 32 + 4 * l5;
#pragma unroll
    for (int tn = 0; tn < 3; ++tn) {
        const int col = cb + tn * 32;
#pragma unroll
        for (int r = 0; r < 16; ++r) {
            int row = rb0 + (r & 3) + 8 * (r >> 2);
            fz[(size_t)row * D_ + col] = acc[tn][r];
        }
    }
}

// ---------------------------------------------------------------------------
// kv2T[b,e,d] = sum_f proj_w[e,f] * (sum_z kvslab[z][b,d,f]) -> packed split
// ---------------------------------------------------------------------------
__global__ __launch_bounds__(256) void kv2_k(
    const float* __restrict__ pw, const float* __restrict__ kvs, size_t span,
    ushort_t* __restrict__ oh, ushort_t* __restrict__ ol)
{
    __shared__ float As[16][68];
    __shared__ float Ws[16][68];
    const int tid = threadIdx.x;
    const int tx = tid & 15, ty = tid >> 4;
    const int m0 = blockIdx.x * 64;   // e
    const int n0 = blockIdx.y * 64;   // d
    const int b = blockIdx.z;
    const int lm = tid >> 2;
    const int lk = (tid & 3) * 4;

    float acc[4][4] = {};
    for (int k0 = 0; k0 < D_; k0 += 16) {
        float4 av = *(const float4*)(pw + (size_t)(m0 + lm) * D_ + k0 + lk);
        As[lk + 0][lm] = av.x; As[lk + 1][lm] = av.y;
        As[lk + 2][lm] = av.z; As[lk + 3][lm] = av.w;
        const float* base = kvs + (size_t)b * D_ * D_ + (size_t)(n0 + lm) * D_ + k0 + lk;
        float4 wv = {0.f, 0.f, 0.f, 0.f};
#pragma unroll
        for (int z = 0; z < 8; ++z) {
            float4 t = *(const float4*)(base + z * span);
            wv.x += t.x; wv.y += t.y; wv.z += t.z; wv.w += t.w;
        }
        Ws[lk + 0][lm] = wv.x; Ws[lk + 1][lm] = wv.y;
        Ws[lk + 2][lm] = wv.z; Ws[lk + 3][lm] = wv.w;
        __syncthreads();
#pragma unroll
        for (int kk = 0; kk < 16; ++kk) {
            float4 a4 = *(const float4*)&As[kk][ty * 4];
            float4 w4 = *(const float4*)&Ws[kk][tx * 4];
            float a[4] = {a4.x, a4.y, a4.z, a4.w};
            float w[4] = {w4.x, w4.y, w4.z, w4.w};
#pragma unroll
            for (int i = 0; i < 4; ++i)
#pragma unroll
                for (int j = 0; j < 4; ++j) acc[i][j] += a[i] * w[j];
        }
        __syncthreads();
    }
    const int d0 = n0 + tx * 4;
#pragma unroll
    for (int i = 0; i < 4; ++i) {
        ushort_t hb[4], lb[4];
#pragma unroll
        for (int j = 0; j < 4; ++j) {
            float v = acc[i][j];
            hb[j] = f2bf(v);
            lb[j] = f2bf(v - bf2f(hb[j]));
        }
        const int e = m0 + ty * 4 + i;
        size_t off = (size_t)b * D_ * D_ + ((size_t)(d0 >> 4) * 192 + e) * 16 + (d0 & 15);
        *(uint2*)&oh[off] = make_uint2((unsigned)hb[0] | ((unsigned)hb[1] << 16),
                                       (unsigned)hb[2] | ((unsigned)hb[3] << 16));
        *(uint2*)&ol[off] = make_uint2((unsigned)lb[0] | ((unsigned)lb[1] << 16),
                                       (unsigned)lb[2] | ((unsigned)lb[3] << 16));
    }
}

// ---------------------------------------------------------------------------
__global__ __launch_bounds__(192) void head_k(
    const float* __restrict__ pooled, const float* __restrict__ hw,
    const float* __restrict__ hb, float* __restrict__ out)
{
    const int b = blockIdx.x, d = threadIdx.x;
    __shared__ float p[D_];
    p[d] = pooled[(size_t)b * D_ + d] * (1.f / N_);
    __syncthreads();
    if (d < NC_) {
        float acc = hb[d];
        for (int e = 0; e < D_; ++e) acc += p[e] * hw[d * D_ + e];
        out[b * NC_ + d] = acc;
    }
}

// ---------------------------------------------------------------------------
extern "C" void kernel_launch(void* const* d_in, const int* in_sizes, int n_in,
                              void* d_out, int out_size, void* d_ws, size_t ws_size,
                              hipStream_t stream) {
    (void)in_sizes; (void)n_in; (void)out_size;

    const float* x      = (const float*)d_in[0];
    const float* conv_w = (const float*)d_in[1];
    const float* conv_b = (const float*)d_in[2];
    const float* pos    = (const float*)d_in[3];
    const float* qkv_w  = (const float*)d_in[4];
    const float* qkv_b  = (const float*)d_in[5];
    const float* proj_w = (const float*)d_in[6];
    const float* proj_b = (const float*)d_in[7];
    const float* ln1_g  = (const float*)d_in[8];
    const float* ln1_b  = (const float*)d_in[9];
    const float* mlp_w1 = (const float*)d_in[10];
    const float* mlp_b1 = (const float*)d_in[11];
    const float* mlp_w2 = (const float*)d_in[12];
    const float* mlp_b2 = (const float*)d_in[13];
    const float* ln2_g  = (const float*)d_in[14];
    const float* ln2_b  = (const float*)d_in[15];
    const float* head_w = (const float*)d_in[16];
    const float* head_b = (const float*)d_in[17];
    float* out = (float*)d_out;

    const size_t perB =
        (size_t)N_ * D_ * 4 +            // h
        (size_t)N_ * D_ * 2 * 2 +        // hn hi+lo (aliased by kv slabs)
        (size_t)N_ * D_ * 2 * 2 +        // q hi+lo
        (size_t)N_ * D_ * 2 * 4 +        // kT,vT hi+lo
        (size_t)D_ * D_ * 2 * 2 +        // kv2t hi+lo (packed)
        16384;
    const size_t fixedW = 2ull * (576 * 192 + 384 * 192 + 192 * 384) * 2 + 65536;
    int BC = B_;
    while (BC > 1 && fixedW + (size_t)BC * perB > ws_size) BC >>= 1;
    const int nchunks = B_ / BC;
    const size_t rows = (size_t)BC * N_;

    char* p = (char*)d_ws;
    auto alloc = [&](size_t bytes) -> char* {
        char* r = p;
        p += (bytes + 255) & ~(size_t)255;
        return r;
    };
    ushort_t* qw_hi = (ushort_t*)alloc(576 * 192 * 2);
    ushort_t* qw_lo = (ushort_t*)alloc(576 * 192 * 2);
    ushort_t* w1_hi = (ushort_t*)alloc(384 * 192 * 2);
    ushort_t* w1_lo = (ushort_t*)alloc(384 * 192 * 2);
    ushort_t* w2_hi = (ushort_t*)alloc(192 * 384 * 2);
    ushort_t* w2_lo = (ushort_t*)alloc(192 * 384 * 2);

    const size_t szPl = rows * D_ * 2;
    float*    h      = (float*)alloc(rows * D_ * 4);
    ushort_t* hn_hi  = (ushort_t*)alloc(szPl);
    ushort_t* hn_lo  = (ushort_t*)alloc(szPl);
    ushort_t* q_hi   = (ushort_t*)alloc(szPl);
    ushort_t* q_lo   = (ushort_t*)alloc(szPl);
    ushort_t* kT_hi  = (ushort_t*)alloc(szPl);
    ushort_t* kT_lo  = (ushort_t*)alloc(szPl);
    ushort_t* vT_hi  = (ushort_t*)alloc(szPl);
    ushort_t* vT_lo  = (ushort_t*)alloc(szPl);
    ushort_t* kv2t_h = (ushort_t*)alloc((size_t)BC * D_ * D_ * 2);
    ushort_t* kv2t_l = (ushort_t*)alloc((size_t)BC * D_ * D_ * 2);
    float*    dsum   = (float*)alloc((size_t)BC * 32 * 4);
    float*    pooled = (float*)alloc((size_t)BC * D_ * 4);
    float*    kvs    = (float*)hn_hi;       // 8 kv slabs alias hn (dead there)
    const size_t kvspan = (size_t)BC * D_ * D_;

    splitw_pack_k<<<(576 * 192 + 255) / 256, 256, 0, stream>>>(qkv_w, qw_hi, qw_lo, 576, 192);
    splitw_pack_k<<<(384 * 192 + 255) / 256, 256, 0, stream>>>(mlp_w1, w1_hi, w1_lo, 384, 192);
    splitw_pack_k<<<(192 * 384 + 255) / 256, 256, 0, stream>>>(mlp_w2, w2_hi, w2_lo, 192, 384);

    const int gm = (int)(rows / 64);
    const size_t SHQ = 50688;                              // mgemm planes + scratch
    const size_t SHG = (size_t)APAD * 2 * 2;               // fused_mlp_g padded planes
    const size_t SH4 = (size_t)(64 * 64 + 12288) * 2 * 2;  // kv dbuf

    for (int ch = 0; ch < nchunks; ++ch) {
        const int b0 = ch * BC;
        const float* xc = x + (size_t)b0 * C_ * N_;

        hipMemsetAsync(pooled, 0, (size_t)BC * D_ * 4, stream);

        // 1. conv + pos + LN1 + split
        conv_ln_k<<<dim3(N_ / 64, BC), 192, 0, stream>>>(
            xc, conv_w, conv_b, pos, ln1_g, ln1_b, h, hn_hi, hn_lo);
        // 2. qkv: q split + qsum slots; k,v blocked transposed split
        mgemm<0, 192, 3><<<gm * 3, 256, SHQ, stream>>>(
            hn_hi, hn_lo, qw_hi, qw_lo, qkv_b, dsum, nullptr, nullptr,
            q_hi, q_lo, kT_hi, kT_lo, vT_hi, vT_lo, nullptr, nullptr);
        // 3. kv z-slabs = k^T v (K-split 8, plain stores into hn-aliased slabs)
        mgemm_kv<<<dim3(BC * 3, 1, 8), 256, SH4, stream>>>(
            kT_hi, kT_lo, vT_hi, vT_lo, kvs, kvspan);
        // 4. kv2T = proj_w @ (sum slabs)^T -> packed split
        kv2_k<<<dim3(3, 3, BC), 256, 0, stream>>>(proj_w, kvs, kvspan, kv2t_h, kv2t_l);
        // 5. v = h + (q@kv2)/denom + proj_b; pool partial of v; LN2+split -> hn
        mgemm<3, 192, 1><<<gm, 256, SHQ, stream>>>(
            q_hi, q_lo, kv2t_h, kv2t_l, proj_b, dsum, ln2_g, ln2_b,
            hn_hi, hn_lo, nullptr, nullptr, nullptr, nullptr, h, pooled);
        // 6. fused MLP group-split: pool += mlp partial sums (no h writes)
        fused_mlp_g<<<gm * 2, 256, SHG, stream>>>(
            hn_hi, hn_lo, w1_hi, w1_lo, w2_hi, w2_lo, mlp_b1, mlp_b2, pooled);
        // 7. head
        head_k<<<BC, 192, 0, stream>>>(pooled, head_w, head_b, out + (size_t)b0 * NC_);
    }
}